// Round 3
// baseline (280.370 us; speedup 1.0000x reference)
//
#include <hip/hip_runtime.h>

// ---------- types ----------
using bf16x8 = __attribute__((ext_vector_type(8))) short;
using v8bf   = __attribute__((ext_vector_type(8))) __bf16;
using f32x4  = __attribute__((ext_vector_type(4))) float;

typedef const __attribute__((address_space(1))) void GASV;
typedef __attribute__((address_space(3))) void LASV;

template <typename V>
__device__ __forceinline__ auto mfma_bf16_impl(V a, V b, f32x4 c, int)
    -> decltype(__builtin_amdgcn_mfma_f32_16x16x32_bf16(a, b, c, 0, 0, 0)) {
  return __builtin_amdgcn_mfma_f32_16x16x32_bf16(a, b, c, 0, 0, 0);
}
template <typename V>
__device__ __forceinline__ f32x4 mfma_bf16_impl(V a, V b, f32x4 c, long) {
  return __builtin_amdgcn_mfma_f32_16x16x32_bf16(
      __builtin_bit_cast(v8bf, a), __builtin_bit_cast(v8bf, b), c, 0, 0, 0);
}
__device__ __forceinline__ f32x4 MFMA(bf16x8 a, bf16x8 b, f32x4 c) {
  return mfma_bf16_impl(a, b, c, 0);
}

__device__ __forceinline__ void async_lds16(const void* g, void* l) {
  __builtin_amdgcn_global_load_lds((GASV*)g, (LASV*)l, 16, 0, 0);
}

__device__ __forceinline__ unsigned short f2bf(float x) {
  unsigned u = __float_as_uint(x);
  u = u + 0x7fffu + ((u >> 16) & 1u);
  return (unsigned short)(u >> 16);
}

#define LOG2E 1.4426950408889634f

// ---------- converters ----------
__global__ __launch_bounds__(256) void k_cvt_x(const float4* __restrict__ x,
                                               ushort4* __restrict__ o) {
  int i = blockIdx.x * 256 + threadIdx.x;
  float4 v = x[i];
  ushort4 p;
  p.x = f2bf(v.x); p.y = f2bf(v.y); p.z = f2bf(v.z); p.w = f2bf(v.w);
  o[i] = p;
}

// out[z][n][k] = W_z[k][n], bf16
__global__ __launch_bounds__(256) void k_transpose_w(
    const float* __restrict__ w0, const float* __restrict__ w1,
    const float* __restrict__ w2, const float* __restrict__ w3,
    const float* __restrict__ w4, unsigned short* __restrict__ out) {
  __shared__ float t[32][33];
  const int z = blockIdx.z;
  const float* W = (z == 0) ? w0 : (z == 1) ? w1 : (z == 2) ? w2 : (z == 3) ? w3 : w4;
  unsigned short* o = out + (size_t)z * (1u << 20);
  const int bx = blockIdx.x * 32, by = blockIdx.y * 32;
  const int tx = threadIdx.x, ty = threadIdx.y;
#pragma unroll
  for (int i = 0; i < 4; ++i)
    t[ty + i * 8][tx] = W[(size_t)(by + ty + i * 8) * 1024 + bx + tx];
  __syncthreads();
#pragma unroll
  for (int i = 0; i < 4; ++i)
    o[(size_t)(bx + ty + i * 8) * 1024 + by + tx] = f2bf(t[tx][ty + i * 8]);
}

// ---------- templated NT GEMM core (K=1024): tile (MI*32) x (NI*32) ----------
template <int MI, int NI>
__device__ __forceinline__ void gemm_core_t(const unsigned short* __restrict__ A,
                                            const unsigned short* __restrict__ Bt,
                                            unsigned short* ldsA,
                                            unsigned short* ldsB,
                                            f32x4 acc[MI][NI]) {
  const int tid = threadIdx.x;
  const int w = tid >> 6, lane = tid & 63;
  const int lane15 = lane & 15, quad = lane >> 4;
  const int wm = w >> 1, wn = w & 1;
  for (int ko = 0; ko < 32; ++ko) {
    __syncthreads();
#pragma unroll
    for (int i = 0; i < MI / 2; ++i) {
      const int p = i * 256 + tid;
      async_lds16(A + (p >> 2) * 1024 + ko * 32 + (p & 3) * 8,
                  ldsA + (i * 256 + w * 64) * 8);
    }
#pragma unroll
    for (int i = 0; i < NI / 2; ++i) {
      const int p = i * 256 + tid;
      async_lds16(Bt + (p >> 2) * 1024 + ko * 32 + (p & 3) * 8,
                  ldsB + (i * 256 + w * 64) * 8);
    }
    __syncthreads();
    bf16x8 af[MI], bfr[NI];
#pragma unroll
    for (int t = 0; t < MI; ++t)
      af[t] = *(const bf16x8*)&ldsA[(wm * (MI * 16) + t * 16 + lane15) * 32 + quad * 8];
#pragma unroll
    for (int t = 0; t < NI; ++t)
      bfr[t] = *(const bf16x8*)&ldsB[(wn * (NI * 16) + t * 16 + lane15) * 32 + quad * 8];
#pragma unroll
    for (int mi = 0; mi < MI; ++mi)
#pragma unroll
      for (int ni = 0; ni < NI; ++ni)
        acc[mi][ni] = MFMA(af[mi], bfr[ni], acc[mi][ni]);
  }
}

#define GEMM_PROLOGUE(MI_, NI_)                                      \
  __shared__ unsigned short ldsA[(MI_)*32 * 32];                     \
  __shared__ unsigned short ldsB[(NI_)*32 * 32];                     \
  f32x4 acc[MI_][NI_];                                               \
  {                                                                  \
    f32x4 z_ = {0.f, 0.f, 0.f, 0.f};                                 \
    for (int i_ = 0; i_ < (MI_); ++i_)                               \
      for (int j_ = 0; j_ < (NI_); ++j_) acc[i_][j_] = z_;           \
  }

#define GEMM_EPI_IDX(MI_, NI_)                                       \
  const int tid = threadIdx.x, w = tid >> 6, lane = tid & 63;        \
  const int lane15 = lane & 15, quad = lane >> 4;                    \
  const int wm = w >> 1, wn = w & 1;                                 \
  const int r0 = tm + wm * ((MI_)*16) + quad * 4;                    \
  const int c0 = tn + wn * ((NI_)*16) + lane15;

// z: 0=pre(silu,+bpre) 1=q(*log2e/8) 2=k -> computed as C^T (A=W,B=x) so
// a lane's 4 acc regs are 4 consecutive outdims at one seq -> ushort4 stores.
// z=3 v: computed as C (A=x,B=W) so rr spans seq -> ushort4 into vt[d][seq].
__global__ __launch_bounds__(256) void k_gemm_qkvpre(
    const unsigned short* __restrict__ xb, const unsigned short* __restrict__ wt,
    const float* __restrict__ bpre, unsigned short* __restrict__ pre,
    unsigned short* __restrict__ qb, unsigned short* __restrict__ kb,
    unsigned short* __restrict__ vt) {
  const int z = blockIdx.z;
  int tm, tn;
  if (z == 3) { tm = blockIdx.y * 128; tn = blockIdx.x * 128; }
  else        { tm = blockIdx.x * 128; tn = blockIdx.y * 128; }
  const unsigned short* At =
      (z == 3) ? xb + (size_t)tm * 1024
               : wt + (size_t)z * (1u << 20) + (size_t)tm * 1024;
  const unsigned short* Bt_ =
      (z == 3) ? wt + (size_t)3 * (1u << 20) + (size_t)tn * 1024
               : xb + (size_t)tn * 1024;
  GEMM_PROLOGUE(4, 4);
  gemm_core_t<4, 4>(At, Bt_, ldsA, ldsB, acc);
  GEMM_EPI_IDX(4, 4);
  if (z == 0) {
#pragma unroll
    for (int mi = 0; mi < 4; ++mi) {
      const float4 b4 = *(const float4*)&bpre[r0 + mi * 16];
#pragma unroll
      for (int ni = 0; ni < 4; ++ni) {
        const int seq = c0 + ni * 16;
        float vv[4];
#pragma unroll
        for (int rr = 0; rr < 4; ++rr) {
          float v = acc[mi][ni][rr] + ((const float*)&b4)[rr];
          vv[rr] = v / (1.0f + __expf(-v));
        }
        ushort4 pk;
        pk.x = f2bf(vv[0]); pk.y = f2bf(vv[1]);
        pk.z = f2bf(vv[2]); pk.w = f2bf(vv[3]);
        *(ushort4*)&pre[(size_t)seq * 1024 + r0 + mi * 16] = pk;
      }
    }
  } else if (z == 1) {
#pragma unroll
    for (int mi = 0; mi < 4; ++mi)
#pragma unroll
      for (int ni = 0; ni < 4; ++ni) {
        const int seq = c0 + ni * 16;
        ushort4 pk;
        pk.x = f2bf(acc[mi][ni][0] * (LOG2E / 8.0f));
        pk.y = f2bf(acc[mi][ni][1] * (LOG2E / 8.0f));
        pk.z = f2bf(acc[mi][ni][2] * (LOG2E / 8.0f));
        pk.w = f2bf(acc[mi][ni][3] * (LOG2E / 8.0f));
        *(ushort4*)&qb[(size_t)seq * 1024 + r0 + mi * 16] = pk;
      }
  } else if (z == 2) {
#pragma unroll
    for (int mi = 0; mi < 4; ++mi)
#pragma unroll
      for (int ni = 0; ni < 4; ++ni) {
        const int seq = c0 + ni * 16;
        ushort4 pk;
        pk.x = f2bf(acc[mi][ni][0]); pk.y = f2bf(acc[mi][ni][1]);
        pk.z = f2bf(acc[mi][ni][2]); pk.w = f2bf(acc[mi][ni][3]);
        *(ushort4*)&kb[(size_t)seq * 1024 + r0 + mi * 16] = pk;
      }
  } else {
#pragma unroll
    for (int mi = 0; mi < 4; ++mi) {
      const int m = r0 + mi * 16;
      const int bb_ = m >> 10, nseq = m & 1023;
#pragma unroll
      for (int ni = 0; ni < 4; ++ni) {
        const int cg = c0 + ni * 16;
        const int hh = cg >> 6, dd = cg & 63;
        ushort4 pk;
        pk.x = f2bf(acc[mi][ni][0]); pk.y = f2bf(acc[mi][ni][1]);
        pk.z = f2bf(acc[mi][ni][2]); pk.w = f2bf(acc[mi][ni][3]);
        *(ushort4*)&vt[(size_t)(((bb_ * 16 + hh) << 6) + dd) * 1024 + nseq] = pk;
      }
    }
  }
}

// Lg[b][i][j] = (pi*log2e/32) * dot(pre_i, pre_j); symmetric -> store
// lg[col][row] so rr packs into ushort4.
__global__ __launch_bounds__(256) void k_gemm_logits(
    const unsigned short* __restrict__ pre, const float* __restrict__ pi,
    unsigned short* __restrict__ lg) {
  const int bz = blockIdx.z;
  const unsigned short* base = pre + ((size_t)bz << 20);
  const int tm = blockIdx.y * 64, tn = blockIdx.x * 128;
  GEMM_PROLOGUE(2, 4);
  gemm_core_t<2, 4>(base + (size_t)tm * 1024, base + (size_t)tn * 1024, ldsA, ldsB, acc);
  const float sc = pi[0] * (LOG2E / 32.0f);
  GEMM_EPI_IDX(2, 4);
#pragma unroll
  for (int mi = 0; mi < 2; ++mi)
#pragma unroll
    for (int ni = 0; ni < 4; ++ni) {
      const int col = c0 + ni * 16;
      ushort4 pk;
      pk.x = f2bf(acc[mi][ni][0] * sc); pk.y = f2bf(acc[mi][ni][1] * sc);
      pk.z = f2bf(acc[mi][ni][2] * sc); pk.w = f2bf(acc[mi][ni][3] * sc);
      *(ushort4*)&lg[((size_t)bz << 20) + (size_t)col * 1024 + r0 + mi * 16] = pk;
    }
}

// out = ao @ Wproj + bproj + x, computed as C^T (A=Wproj^T rows, B=ao rows)
// -> float4 stores along outdim.
__global__ __launch_bounds__(256) void k_gemm_out(
    const unsigned short* __restrict__ ao, const unsigned short* __restrict__ wtp,
    const float* __restrict__ bproj, const float* __restrict__ xres,
    float* __restrict__ out) {
  const int tm = blockIdx.x * 64, tn = blockIdx.y * 128;
  GEMM_PROLOGUE(2, 4);
  gemm_core_t<2, 4>(wtp + (size_t)tm * 1024, ao + (size_t)tn * 1024, ldsA, ldsB, acc);
  GEMM_EPI_IDX(2, 4);
#pragma unroll
  for (int mi = 0; mi < 2; ++mi) {
    const float4 b4 = *(const float4*)&bproj[r0 + mi * 16];
#pragma unroll
    for (int ni = 0; ni < 4; ++ni) {
      const int seq = c0 + ni * 16;
      const size_t idx = (size_t)seq * 1024 + r0 + mi * 16;
      const float4 rv = *(const float4*)&xres[idx];
      float4 ov;
      ov.x = acc[mi][ni][0] + b4.x + rv.x;
      ov.y = acc[mi][ni][1] + b4.y + rv.y;
      ov.z = acc[mi][ni][2] + b4.z + rv.z;
      ov.w = acc[mi][ni][3] + b4.w + rv.w;
      *(float4*)&out[idx] = ov;
    }
  }
}

// ---------- fused flash attention, S^T = K q^T layout ----------
// grid (16,16,4): 64 q/block (16/wave), KV chunks of 128.
// P aliases ldsK (K dead after S): LDS 32 KB -> 5 blocks/CU.
// Bias lg seeds the S accumulator (no separate add pass).
__global__ __launch_bounds__(256, 5) void k_attn(
    const unsigned short* __restrict__ qb, const unsigned short* __restrict__ kb,
    const unsigned short* __restrict__ vt, const unsigned short* __restrict__ lg,
    unsigned short* __restrict__ ao) {
  __shared__ unsigned short ldsK[128 * 64];  // [kv][d] swz ^(kv&7); then P
  __shared__ unsigned short ldsV[64 * 128];  // [d][kv] swz ^(d&15)
  const int b = blockIdx.z, h = blockIdx.y, q0 = blockIdx.x * 64;
  const int tid = threadIdx.x, w = tid >> 6, lane = tid & 63;
  const int lane15 = lane & 15, quad = lane >> 4;
  const int qw = q0 + w * 16;
  char* Pb = (char*)(ldsK + w * 2048);  // per-wave 4 KB P region

  bf16x8 qf[2];
  {
    const unsigned short* qrow =
        qb + (size_t)((b << 10) + qw + lane15) * 1024 + (h << 6);
    qf[0] = *(const bf16x8*)(qrow + quad * 8);
    qf[1] = *(const bf16x8*)(qrow + 32 + quad * 8);
  }
  float mcol = -__builtin_inff(), lcol = 0.f;
  f32x4 o[4];
  {
    f32x4 z_ = {0.f, 0.f, 0.f, 0.f};
#pragma unroll
    for (int nt = 0; nt < 4; ++nt) o[nt] = z_;
  }

  for (int c = 0; c < 8; ++c) {
    const int kv0 = c * 128;
    __syncthreads();  // prev chunk P/V reads complete
#pragma unroll
    for (int i = 0; i < 4; ++i) {
      const int p = i * 256 + tid;
      {
        const int r = p >> 3, cc = (p & 7) ^ (r & 7);
        async_lds16(kb + (size_t)((b << 10) + kv0 + r) * 1024 + (h << 6) + cc * 8,
                    ldsK + (i * 256 + w * 64) * 8);
      }
      {
        const int r = p >> 4, cc = (p & 15) ^ (r & 15);
        async_lds16(vt + (size_t)(((b * 16 + h) << 6) + r) * 1024 + kv0 + cc * 8,
                    ldsV + (i * 256 + w * 64) * 8);
      }
    }
    uint2 lgv[8];
    {
      const unsigned short* lgrow =
          lg + ((size_t)b << 20) + (size_t)(qw + lane15) * 1024 + kv0 + quad * 4;
#pragma unroll
      for (int mi = 0; mi < 8; ++mi) lgv[mi] = *(const uint2*)(lgrow + mi * 16);
    }
    __syncthreads();  // staging visible

    // S^T = K q^T, accumulator seeded with bias
    f32x4 s[8];
#pragma unroll
    for (int mi = 0; mi < 8; ++mi) {
      const int row = mi * 16 + lane15;
      bf16x8 k0 = *(const bf16x8*)&ldsK[row * 64 + ((quad ^ (row & 7)) << 3)];
      bf16x8 k1 = *(const bf16x8*)&ldsK[row * 64 + (((4 + quad) ^ (row & 7)) << 3)];
      f32x4 t;
      t[0] = __uint_as_float(lgv[mi].x << 16);
      t[1] = __uint_as_float(lgv[mi].x & 0xffff0000u);
      t[2] = __uint_as_float(lgv[mi].y << 16);
      t[3] = __uint_as_float(lgv[mi].y & 0xffff0000u);
      t = MFMA(k0, qf[0], t);
      t = MFMA(k1, qf[1], t);
      s[mi] = t;
    }
    // online softmax over kv (exp2 domain)
    float mx = s[0][0];
#pragma unroll
    for (int mi = 0; mi < 8; ++mi)
#pragma unroll
      for (int rr = 0; rr < 4; ++rr) mx = fmaxf(mx, s[mi][rr]);
    mx = fmaxf(mx, __shfl_xor(mx, 16));
    mx = fmaxf(mx, __shfl_xor(mx, 32));
    const float mn = fmaxf(mcol, mx);
    const float al = exp2f(mcol - mn);
    mcol = mn;
    float rs = 0.f;
    uint2 pk[8];
#pragma unroll
    for (int mi = 0; mi < 8; ++mi) {
      const float p0 = exp2f(s[mi][0] - mn), p1 = exp2f(s[mi][1] - mn);
      const float p2 = exp2f(s[mi][2] - mn), p3 = exp2f(s[mi][3] - mn);
      rs += (p0 + p1) + (p2 + p3);
      pk[mi].x = ((__float_as_uint(p1) + 0x8000u) & 0xffff0000u) |
                 ((__float_as_uint(p0) + 0x8000u) >> 16);
      pk[mi].y = ((__float_as_uint(p3) + 0x8000u) & 0xffff0000u) |
                 ((__float_as_uint(p2) + 0x8000u) >> 16);
    }
    rs += __shfl_xor(rs, 16);
    rs += __shfl_xor(rs, 32);
    lcol = lcol * al + rs;
    float ar[4];
#pragma unroll
    for (int rr = 0; rr < 4; ++rr) ar[rr] = __shfl(al, quad * 4 + rr);
#pragma unroll
    for (int nt = 0; nt < 4; ++nt)
#pragma unroll
      for (int rr = 0; rr < 4; ++rr) o[nt][rr] *= ar[rr];

    __syncthreads();  // all waves done reading K; P may overwrite it
#pragma unroll
    for (int mi = 0; mi < 8; ++mi)
      *(uint2*)(Pb + lane15 * 256 + (((2 * mi + (quad >> 1)) ^ lane15) << 4) +
                ((quad & 1) << 3)) = pk[mi];
    // O += P V
#pragma unroll
    for (int ks = 0; ks < 4; ++ks) {
      bf16x8 pf = *(const bf16x8*)(Pb + lane15 * 256 +
                                   ((((ks << 2) + quad) ^ lane15) << 4));
#pragma unroll
      for (int nt = 0; nt < 4; ++nt) {
        const int d = nt * 16 + lane15;
        bf16x8 vf = *(const bf16x8*)&ldsV[d * 128 +
                                          (((ks * 4 + quad) ^ (d & 15)) << 3)];
        o[nt] = MFMA(pf, vf, o[nt]);
      }
    }
  }
  // normalize + store [B*N, H*Dh] bf16
  const float rinv = 1.0f / lcol;
  float rv[4];
#pragma unroll
  for (int rr = 0; rr < 4; ++rr) rv[rr] = __shfl(rinv, quad * 4 + rr);
#pragma unroll
  for (int nt = 0; nt < 4; ++nt) {
    const int cg = (h << 6) + nt * 16 + lane15;
#pragma unroll
    for (int rr = 0; rr < 4; ++rr) {
      const int m = (b << 10) + qw + quad * 4 + rr;
      ao[(size_t)m * 1024 + cg] = f2bf(o[nt][rr] * rv[rr]);
    }
  }
}

// ---------- launch ----------
extern "C" void kernel_launch(void* const* d_in, const int* in_sizes, int n_in,
                              void* d_out, int out_size, void* d_ws, size_t ws_size,
                              hipStream_t stream) {
  const float* x     = (const float*)d_in[0];
  const float* Wq    = (const float*)d_in[1];
  const float* Wk    = (const float*)d_in[2];
  const float* Wv    = (const float*)d_in[3];
  const float* Wproj = (const float*)d_in[4];
  const float* bproj = (const float*)d_in[5];
  const float* Wpre  = (const float*)d_in[6];
  const float* bpre  = (const float*)d_in[7];
  const float* pi    = (const float*)d_in[8];
  float* out = (float*)d_out;
  char* ws = (char*)d_ws;

  unsigned short* xb  = (unsigned short*)(ws);               // 8 MB (later: lg)
  unsigned short* wt  = (unsigned short*)(ws + (8u << 20));  // 10 MB
  unsigned short* pre = (unsigned short*)(ws + (18u << 20)); // 8 MB (later: ao)
  unsigned short* qb  = (unsigned short*)(ws + (26u << 20)); // 8 MB
  unsigned short* kb  = (unsigned short*)(ws + (34u << 20)); // 8 MB
  unsigned short* vt  = (unsigned short*)(ws + (42u << 20)); // 8 MB
  unsigned short* lg  = xb;   // xb dead after k_gemm_qkvpre
  unsigned short* ao  = pre;  // pre dead after k_gemm_logits

  k_cvt_x<<<dim3(4096), dim3(256), 0, stream>>>((const float4*)x, (ushort4*)xb);
  k_transpose_w<<<dim3(32, 32, 5), dim3(32, 8), 0, stream>>>(Wpre, Wq, Wk, Wv, Wproj, wt);
  k_gemm_qkvpre<<<dim3(8, 32, 4), dim3(256), 0, stream>>>(xb, wt, bpre, pre, qb, kb, vt);
  k_gemm_logits<<<dim3(8, 16, 4), dim3(256), 0, stream>>>(pre, pi, lg);
  k_attn<<<dim3(16, 16, 4), dim3(256), 0, stream>>>(qb, kb, vt, lg, ao);
  k_gemm_out<<<dim3(16, 32, 1), dim3(256), 0, stream>>>(ao, wt + 4 * (1u << 20), bproj, x, out);
}

// Round 4
// 264.388 us; speedup vs baseline: 1.0604x; 1.0604x over previous
//
#include <hip/hip_runtime.h>

// ---------- types ----------
using bf16x8 = __attribute__((ext_vector_type(8))) short;
using v8bf   = __attribute__((ext_vector_type(8))) __bf16;
using f32x4  = __attribute__((ext_vector_type(4))) float;

typedef const __attribute__((address_space(1))) void GASV;
typedef __attribute__((address_space(3))) void LASV;

template <typename V>
__device__ __forceinline__ auto mfma_bf16_impl(V a, V b, f32x4 c, int)
    -> decltype(__builtin_amdgcn_mfma_f32_16x16x32_bf16(a, b, c, 0, 0, 0)) {
  return __builtin_amdgcn_mfma_f32_16x16x32_bf16(a, b, c, 0, 0, 0);
}
template <typename V>
__device__ __forceinline__ f32x4 mfma_bf16_impl(V a, V b, f32x4 c, long) {
  return __builtin_amdgcn_mfma_f32_16x16x32_bf16(
      __builtin_bit_cast(v8bf, a), __builtin_bit_cast(v8bf, b), c, 0, 0, 0);
}
__device__ __forceinline__ f32x4 MFMA(bf16x8 a, bf16x8 b, f32x4 c) {
  return mfma_bf16_impl(a, b, c, 0);
}

__device__ __forceinline__ void async_lds16(const void* g, void* l) {
  __builtin_amdgcn_global_load_lds((GASV*)g, (LASV*)l, 16, 0, 0);
}

__device__ __forceinline__ unsigned short f2bf(float x) {
  unsigned u = __float_as_uint(x);
  u = u + 0x7fffu + ((u >> 16) & 1u);
  return (unsigned short)(u >> 16);
}

#define LOG2E 1.4426950408889634f

// ---------- converters ----------
__global__ __launch_bounds__(256) void k_cvt_x(const float4* __restrict__ x,
                                               ushort4* __restrict__ o) {
  int i = blockIdx.x * 256 + threadIdx.x;
  float4 v = x[i];
  ushort4 p;
  p.x = f2bf(v.x); p.y = f2bf(v.y); p.z = f2bf(v.z); p.w = f2bf(v.w);
  o[i] = p;
}

// out[z][n][k] = W_z[k][n], bf16
__global__ __launch_bounds__(256) void k_transpose_w(
    const float* __restrict__ w0, const float* __restrict__ w1,
    const float* __restrict__ w2, const float* __restrict__ w3,
    const float* __restrict__ w4, unsigned short* __restrict__ out) {
  __shared__ float t[32][33];
  const int z = blockIdx.z;
  const float* W = (z == 0) ? w0 : (z == 1) ? w1 : (z == 2) ? w2 : (z == 3) ? w3 : w4;
  unsigned short* o = out + (size_t)z * (1u << 20);
  const int bx = blockIdx.x * 32, by = blockIdx.y * 32;
  const int tx = threadIdx.x, ty = threadIdx.y;
#pragma unroll
  for (int i = 0; i < 4; ++i)
    t[ty + i * 8][tx] = W[(size_t)(by + ty + i * 8) * 1024 + bx + tx];
  __syncthreads();
#pragma unroll
  for (int i = 0; i < 4; ++i)
    o[(size_t)(bx + ty + i * 8) * 1024 + by + tx] = f2bf(t[tx][ty + i * 8]);
}

// ---------- templated NT GEMM core (K=1024): tile (MI*32) x (NI*32) ----------
template <int MI, int NI>
__device__ __forceinline__ void gemm_core_t(const unsigned short* __restrict__ A,
                                            const unsigned short* __restrict__ Bt,
                                            unsigned short* ldsA,
                                            unsigned short* ldsB,
                                            f32x4 acc[MI][NI]) {
  const int tid = threadIdx.x;
  const int w = tid >> 6, lane = tid & 63;
  const int lane15 = lane & 15, quad = lane >> 4;
  const int wm = w >> 1, wn = w & 1;
  for (int ko = 0; ko < 32; ++ko) {
    __syncthreads();
#pragma unroll
    for (int i = 0; i < MI / 2; ++i) {
      const int p = i * 256 + tid;
      async_lds16(A + (p >> 2) * 1024 + ko * 32 + (p & 3) * 8,
                  ldsA + (i * 256 + w * 64) * 8);
    }
#pragma unroll
    for (int i = 0; i < NI / 2; ++i) {
      const int p = i * 256 + tid;
      async_lds16(Bt + (p >> 2) * 1024 + ko * 32 + (p & 3) * 8,
                  ldsB + (i * 256 + w * 64) * 8);
    }
    __syncthreads();
    bf16x8 af[MI], bfr[NI];
#pragma unroll
    for (int t = 0; t < MI; ++t)
      af[t] = *(const bf16x8*)&ldsA[(wm * (MI * 16) + t * 16 + lane15) * 32 + quad * 8];
#pragma unroll
    for (int t = 0; t < NI; ++t)
      bfr[t] = *(const bf16x8*)&ldsB[(wn * (NI * 16) + t * 16 + lane15) * 32 + quad * 8];
#pragma unroll
    for (int mi = 0; mi < MI; ++mi)
#pragma unroll
      for (int ni = 0; ni < NI; ++ni)
        acc[mi][ni] = MFMA(af[mi], bfr[ni], acc[mi][ni]);
  }
}

#define GEMM_PROLOGUE(MI_, NI_)                                      \
  __shared__ unsigned short ldsA[(MI_)*32 * 32];                     \
  __shared__ unsigned short ldsB[(NI_)*32 * 32];                     \
  f32x4 acc[MI_][NI_];                                               \
  {                                                                  \
    f32x4 z_ = {0.f, 0.f, 0.f, 0.f};                                 \
    for (int i_ = 0; i_ < (MI_); ++i_)                               \
      for (int j_ = 0; j_ < (NI_); ++j_) acc[i_][j_] = z_;           \
  }

#define GEMM_EPI_IDX(MI_, NI_)                                       \
  const int tid = threadIdx.x, w = tid >> 6, lane = tid & 63;        \
  const int lane15 = lane & 15, quad = lane >> 4;                    \
  const int wm = w >> 1, wn = w & 1;                                 \
  const int r0 = tm + wm * ((MI_)*16) + quad * 4;                    \
  const int c0 = tn + wn * ((NI_)*16) + lane15;

// z: 0=pre(silu,+bpre) 1=q(*log2e/8) 2=k -> computed as C^T (A=W,B=x).
// z=3 v: computed as C (A=x,B=W) -> ushort4 into vt[d][seq].
// 1-D grid 1024, XCD swizzle: xcd(bid&7) = z*2 + seq-half, so each XCD's
// L2 holds one weight (2MB) + half of x (4MB).
__global__ __launch_bounds__(256) void k_gemm_qkvpre(
    const unsigned short* __restrict__ xb, const unsigned short* __restrict__ wt,
    const float* __restrict__ bpre, unsigned short* __restrict__ pre,
    unsigned short* __restrict__ qb, unsigned short* __restrict__ kb,
    unsigned short* __restrict__ vt) {
  const int bid = blockIdx.x;
  const int xcd = bid & 7, idx = bid >> 3;
  const int z = xcd >> 1, half = xcd & 1;
  const int wtile = (idx >> 4) * 128;                 // weight/outdim tile
  const int stile = half * 2048 + (idx & 15) * 128;   // seq tile
  int tm, tn;
  if (z == 3) { tm = stile; tn = wtile; }
  else        { tm = wtile; tn = stile; }
  const unsigned short* At =
      (z == 3) ? xb + (size_t)tm * 1024
               : wt + (size_t)z * (1u << 20) + (size_t)tm * 1024;
  const unsigned short* Bt_ =
      (z == 3) ? wt + (size_t)3 * (1u << 20) + (size_t)tn * 1024
               : xb + (size_t)tn * 1024;
  GEMM_PROLOGUE(4, 4);
  gemm_core_t<4, 4>(At, Bt_, ldsA, ldsB, acc);
  GEMM_EPI_IDX(4, 4);
  if (z == 0) {
#pragma unroll
    for (int mi = 0; mi < 4; ++mi) {
      const float4 b4 = *(const float4*)&bpre[r0 + mi * 16];
#pragma unroll
      for (int ni = 0; ni < 4; ++ni) {
        const int seq = c0 + ni * 16;
        float vv[4];
#pragma unroll
        for (int rr = 0; rr < 4; ++rr) {
          float v = acc[mi][ni][rr] + ((const float*)&b4)[rr];
          vv[rr] = v / (1.0f + __expf(-v));
        }
        ushort4 pk;
        pk.x = f2bf(vv[0]); pk.y = f2bf(vv[1]);
        pk.z = f2bf(vv[2]); pk.w = f2bf(vv[3]);
        *(ushort4*)&pre[(size_t)seq * 1024 + r0 + mi * 16] = pk;
      }
    }
  } else if (z == 1) {
#pragma unroll
    for (int mi = 0; mi < 4; ++mi)
#pragma unroll
      for (int ni = 0; ni < 4; ++ni) {
        const int seq = c0 + ni * 16;
        ushort4 pk;
        pk.x = f2bf(acc[mi][ni][0] * (LOG2E / 8.0f));
        pk.y = f2bf(acc[mi][ni][1] * (LOG2E / 8.0f));
        pk.z = f2bf(acc[mi][ni][2] * (LOG2E / 8.0f));
        pk.w = f2bf(acc[mi][ni][3] * (LOG2E / 8.0f));
        *(ushort4*)&qb[(size_t)seq * 1024 + r0 + mi * 16] = pk;
      }
  } else if (z == 2) {
#pragma unroll
    for (int mi = 0; mi < 4; ++mi)
#pragma unroll
      for (int ni = 0; ni < 4; ++ni) {
        const int seq = c0 + ni * 16;
        ushort4 pk;
        pk.x = f2bf(acc[mi][ni][0]); pk.y = f2bf(acc[mi][ni][1]);
        pk.z = f2bf(acc[mi][ni][2]); pk.w = f2bf(acc[mi][ni][3]);
        *(ushort4*)&kb[(size_t)seq * 1024 + r0 + mi * 16] = pk;
      }
  } else {
#pragma unroll
    for (int mi = 0; mi < 4; ++mi) {
      const int m = r0 + mi * 16;
      const int bb_ = m >> 10, nseq = m & 1023;
#pragma unroll
      for (int ni = 0; ni < 4; ++ni) {
        const int cg = c0 + ni * 16;
        const int hh = cg >> 6, dd = cg & 63;
        ushort4 pk;
        pk.x = f2bf(acc[mi][ni][0]); pk.y = f2bf(acc[mi][ni][1]);
        pk.z = f2bf(acc[mi][ni][2]); pk.w = f2bf(acc[mi][ni][3]);
        *(ushort4*)&vt[(size_t)(((bb_ * 16 + hh) << 6) + dd) * 1024 + nseq] = pk;
      }
    }
  }
}

// Lg[b][i][j] = (pi*log2e/32) * dot(pre_i, pre_j); symmetric -> store
// lg[col][row] so rr packs into ushort4.
__global__ __launch_bounds__(256) void k_gemm_logits(
    const unsigned short* __restrict__ pre, const float* __restrict__ pi,
    unsigned short* __restrict__ lg) {
  const int bz = blockIdx.z;
  const unsigned short* base = pre + ((size_t)bz << 20);
  const int tm = blockIdx.y * 64, tn = blockIdx.x * 128;
  GEMM_PROLOGUE(2, 4);
  gemm_core_t<2, 4>(base + (size_t)tm * 1024, base + (size_t)tn * 1024, ldsA, ldsB, acc);
  const float sc = pi[0] * (LOG2E / 32.0f);
  GEMM_EPI_IDX(2, 4);
#pragma unroll
  for (int mi = 0; mi < 2; ++mi)
#pragma unroll
    for (int ni = 0; ni < 4; ++ni) {
      const int col = c0 + ni * 16;
      ushort4 pk;
      pk.x = f2bf(acc[mi][ni][0] * sc); pk.y = f2bf(acc[mi][ni][1] * sc);
      pk.z = f2bf(acc[mi][ni][2] * sc); pk.w = f2bf(acc[mi][ni][3] * sc);
      *(ushort4*)&lg[((size_t)bz << 20) + (size_t)col * 1024 + r0 + mi * 16] = pk;
    }
}

// out = ao @ Wproj + bproj + x, computed as C^T -> float4 stores along outdim.
__global__ __launch_bounds__(256) void k_gemm_out(
    const unsigned short* __restrict__ ao, const unsigned short* __restrict__ wtp,
    const float* __restrict__ bproj, const float* __restrict__ xres,
    float* __restrict__ out) {
  const int tm = blockIdx.x * 64, tn = blockIdx.y * 128;
  GEMM_PROLOGUE(2, 4);
  gemm_core_t<2, 4>(wtp + (size_t)tm * 1024, ao + (size_t)tn * 1024, ldsA, ldsB, acc);
  GEMM_EPI_IDX(2, 4);
#pragma unroll
  for (int mi = 0; mi < 2; ++mi) {
    const float4 b4 = *(const float4*)&bproj[r0 + mi * 16];
#pragma unroll
    for (int ni = 0; ni < 4; ++ni) {
      const int seq = c0 + ni * 16;
      const size_t idx = (size_t)seq * 1024 + r0 + mi * 16;
      const float4 rv = *(const float4*)&xres[idx];
      float4 ov;
      ov.x = acc[mi][ni][0] + b4.x + rv.x;
      ov.y = acc[mi][ni][1] + b4.y + rv.y;
      ov.z = acc[mi][ni][2] + b4.z + rv.z;
      ov.w = acc[mi][ni][3] + b4.w + rv.w;
      *(float4*)&out[idx] = ov;
    }
  }
}

// ---------- fused flash attention, S^T = K q^T layout ----------
// 1-D grid 1024, XCD swizzle: xcd(bid&7) = b*2 + h/8 -> each XCD serves one
// batch's 8 heads: working set lg[b] 2MB + K/V 2MB + q 1MB, L2/L3-resident.
// P aliases ldsK (LDS 32KB -> 5 blocks/CU); bias lg seeds the S accumulator.
__global__ __launch_bounds__(256, 5) void k_attn(
    const unsigned short* __restrict__ qb, const unsigned short* __restrict__ kb,
    const unsigned short* __restrict__ vt, const unsigned short* __restrict__ lg,
    unsigned short* __restrict__ ao) {
  __shared__ unsigned short ldsK[128 * 64];  // [kv][d] swz ^(kv&7); then P
  __shared__ unsigned short ldsV[64 * 128];  // [d][kv] swz ^(d&15)
  const int bid = blockIdx.x;
  const int xcd = bid & 7, idx = bid >> 3;
  const int b = xcd >> 1, hg = xcd & 1;
  const int h = hg * 8 + (idx >> 4);
  const int q0 = (idx & 15) * 64;
  const int tid = threadIdx.x, w = tid >> 6, lane = tid & 63;
  const int lane15 = lane & 15, quad = lane >> 4;
  const int qw = q0 + w * 16;
  char* Pb = (char*)(ldsK + w * 2048);  // per-wave 4 KB P region

  bf16x8 qf[2];
  {
    const unsigned short* qrow =
        qb + (size_t)((b << 10) + qw + lane15) * 1024 + (h << 6);
    qf[0] = *(const bf16x8*)(qrow + quad * 8);
    qf[1] = *(const bf16x8*)(qrow + 32 + quad * 8);
  }
  float mcol = -__builtin_inff(), lcol = 0.f;
  f32x4 o[4];
  {
    f32x4 z_ = {0.f, 0.f, 0.f, 0.f};
#pragma unroll
    for (int nt = 0; nt < 4; ++nt) o[nt] = z_;
  }

  for (int c = 0; c < 8; ++c) {
    const int kv0 = c * 128;
    __syncthreads();  // prev chunk P/V reads complete
#pragma unroll
    for (int i = 0; i < 4; ++i) {
      const int p = i * 256 + tid;
      {
        const int r = p >> 3, cc = (p & 7) ^ (r & 7);
        async_lds16(kb + (size_t)((b << 10) + kv0 + r) * 1024 + (h << 6) + cc * 8,
                    ldsK + (i * 256 + w * 64) * 8);
      }
      {
        const int r = p >> 4, cc = (p & 15) ^ (r & 15);
        async_lds16(vt + (size_t)(((b * 16 + h) << 6) + r) * 1024 + kv0 + cc * 8,
                    ldsV + (i * 256 + w * 64) * 8);
      }
    }
    uint2 lgv[8];
    {
      const unsigned short* lgrow =
          lg + ((size_t)b << 20) + (size_t)(qw + lane15) * 1024 + kv0 + quad * 4;
#pragma unroll
      for (int mi = 0; mi < 8; ++mi) lgv[mi] = *(const uint2*)(lgrow + mi * 16);
    }
    __syncthreads();  // staging visible

    // S^T = K q^T, accumulator seeded with bias
    f32x4 s[8];
#pragma unroll
    for (int mi = 0; mi < 8; ++mi) {
      const int row = mi * 16 + lane15;
      bf16x8 k0 = *(const bf16x8*)&ldsK[row * 64 + ((quad ^ (row & 7)) << 3)];
      bf16x8 k1 = *(const bf16x8*)&ldsK[row * 64 + (((4 + quad) ^ (row & 7)) << 3)];
      f32x4 t;
      t[0] = __uint_as_float(lgv[mi].x << 16);
      t[1] = __uint_as_float(lgv[mi].x & 0xffff0000u);
      t[2] = __uint_as_float(lgv[mi].y << 16);
      t[3] = __uint_as_float(lgv[mi].y & 0xffff0000u);
      t = MFMA(k0, qf[0], t);
      t = MFMA(k1, qf[1], t);
      s[mi] = t;
    }
    // online softmax over kv (exp2 domain)
    float mx = s[0][0];
#pragma unroll
    for (int mi = 0; mi < 8; ++mi)
#pragma unroll
      for (int rr = 0; rr < 4; ++rr) mx = fmaxf(mx, s[mi][rr]);
    mx = fmaxf(mx, __shfl_xor(mx, 16));
    mx = fmaxf(mx, __shfl_xor(mx, 32));
    const float mn = fmaxf(mcol, mx);
    const float al = exp2f(mcol - mn);
    mcol = mn;
    float rs = 0.f;
    uint2 pk[8];
#pragma unroll
    for (int mi = 0; mi < 8; ++mi) {
      const float p0 = exp2f(s[mi][0] - mn), p1 = exp2f(s[mi][1] - mn);
      const float p2 = exp2f(s[mi][2] - mn), p3 = exp2f(s[mi][3] - mn);
      rs += (p0 + p1) + (p2 + p3);
      pk[mi].x = ((__float_as_uint(p1) + 0x8000u) & 0xffff0000u) |
                 ((__float_as_uint(p0) + 0x8000u) >> 16);
      pk[mi].y = ((__float_as_uint(p3) + 0x8000u) & 0xffff0000u) |
                 ((__float_as_uint(p2) + 0x8000u) >> 16);
    }
    rs += __shfl_xor(rs, 16);
    rs += __shfl_xor(rs, 32);
    lcol = lcol * al + rs;
    float ar[4];
#pragma unroll
    for (int rr = 0; rr < 4; ++rr) ar[rr] = __shfl(al, quad * 4 + rr);
#pragma unroll
    for (int nt = 0; nt < 4; ++nt)
#pragma unroll
      for (int rr = 0; rr < 4; ++rr) o[nt][rr] *= ar[rr];

    __syncthreads();  // all waves done reading K; P may overwrite it
#pragma unroll
    for (int mi = 0; mi < 8; ++mi)
      *(uint2*)(Pb + lane15 * 256 + (((2 * mi + (quad >> 1)) ^ lane15) << 4) +
                ((quad & 1) << 3)) = pk[mi];
    // O += P V
#pragma unroll
    for (int ks = 0; ks < 4; ++ks) {
      bf16x8 pf = *(const bf16x8*)(Pb + lane15 * 256 +
                                   ((((ks << 2) + quad) ^ lane15) << 4));
#pragma unroll
      for (int nt = 0; nt < 4; ++nt) {
        const int d = nt * 16 + lane15;
        bf16x8 vf = *(const bf16x8*)&ldsV[d * 128 +
                                          (((ks * 4 + quad) ^ (d & 15)) << 3)];
        o[nt] = MFMA(pf, vf, o[nt]);
      }
    }
  }
  // normalize + store [B*N, H*Dh] bf16
  const float rinv = 1.0f / lcol;
  float rv[4];
#pragma unroll
  for (int rr = 0; rr < 4; ++rr) rv[rr] = __shfl(rinv, quad * 4 + rr);
#pragma unroll
  for (int nt = 0; nt < 4; ++nt) {
    const int cg = (h << 6) + nt * 16 + lane15;
#pragma unroll
    for (int rr = 0; rr < 4; ++rr) {
      const int m = (b << 10) + qw + quad * 4 + rr;
      ao[(size_t)m * 1024 + cg] = f2bf(o[nt][rr] * rv[rr]);
    }
  }
}

// ---------- launch ----------
extern "C" void kernel_launch(void* const* d_in, const int* in_sizes, int n_in,
                              void* d_out, int out_size, void* d_ws, size_t ws_size,
                              hipStream_t stream) {
  const float* x     = (const float*)d_in[0];
  const float* Wq    = (const float*)d_in[1];
  const float* Wk    = (const float*)d_in[2];
  const float* Wv    = (const float*)d_in[3];
  const float* Wproj = (const float*)d_in[4];
  const float* bproj = (const float*)d_in[5];
  const float* Wpre  = (const float*)d_in[6];
  const float* bpre  = (const float*)d_in[7];
  const float* pi    = (const float*)d_in[8];
  float* out = (float*)d_out;
  char* ws = (char*)d_ws;

  unsigned short* xb  = (unsigned short*)(ws);               // 8 MB (later: lg)
  unsigned short* wt  = (unsigned short*)(ws + (8u << 20));  // 10 MB
  unsigned short* pre = (unsigned short*)(ws + (18u << 20)); // 8 MB (later: ao)
  unsigned short* qb  = (unsigned short*)(ws + (26u << 20)); // 8 MB
  unsigned short* kb  = (unsigned short*)(ws + (34u << 20)); // 8 MB
  unsigned short* vt  = (unsigned short*)(ws + (42u << 20)); // 8 MB
  unsigned short* lg  = xb;   // xb dead after k_gemm_qkvpre
  unsigned short* ao  = pre;  // pre dead after k_gemm_logits

  k_cvt_x<<<dim3(4096), dim3(256), 0, stream>>>((const float4*)x, (ushort4*)xb);
  k_transpose_w<<<dim3(32, 32, 5), dim3(32, 8), 0, stream>>>(Wpre, Wq, Wk, Wv, Wproj, wt);
  k_gemm_qkvpre<<<dim3(1024), dim3(256), 0, stream>>>(xb, wt, bpre, pre, qb, kb, vt);
  k_gemm_logits<<<dim3(8, 16, 4), dim3(256), 0, stream>>>(pre, pi, lg);
  k_attn<<<dim3(1024), dim3(256), 0, stream>>>(qb, kb, vt, lg, ao);
  k_gemm_out<<<dim3(16, 32, 1), dim3(256), 0, stream>>>(ao, wt + 4 * (1u << 20), bproj, x, out);
}

// Round 5
// 256.838 us; speedup vs baseline: 1.0916x; 1.0294x over previous
//
#include <hip/hip_runtime.h>

// ---------- types ----------
using bf16x8 = __attribute__((ext_vector_type(8))) short;
using v8bf   = __attribute__((ext_vector_type(8))) __bf16;
using f32x4  = __attribute__((ext_vector_type(4))) float;

typedef const __attribute__((address_space(1))) void GASV;
typedef __attribute__((address_space(3))) void LASV;

template <typename V>
__device__ __forceinline__ auto mfma_bf16_impl(V a, V b, f32x4 c, int)
    -> decltype(__builtin_amdgcn_mfma_f32_16x16x32_bf16(a, b, c, 0, 0, 0)) {
  return __builtin_amdgcn_mfma_f32_16x16x32_bf16(a, b, c, 0, 0, 0);
}
template <typename V>
__device__ __forceinline__ f32x4 mfma_bf16_impl(V a, V b, f32x4 c, long) {
  return __builtin_amdgcn_mfma_f32_16x16x32_bf16(
      __builtin_bit_cast(v8bf, a), __builtin_bit_cast(v8bf, b), c, 0, 0, 0);
}
__device__ __forceinline__ f32x4 MFMA(bf16x8 a, bf16x8 b, f32x4 c) {
  return mfma_bf16_impl(a, b, c, 0);
}

__device__ __forceinline__ void async_lds16(const void* g, void* l) {
  __builtin_amdgcn_global_load_lds((GASV*)g, (LASV*)l, 16, 0, 0);
}

__device__ __forceinline__ unsigned short f2bf(float x) {
  unsigned u = __float_as_uint(x);
  u = u + 0x7fffu + ((u >> 16) & 1u);
  return (unsigned short)(u >> 16);
}

#define LOG2E 1.4426950408889634f
#define SOFT_OFF 14.0f  // fixed softmax offset (exp2 domain); |s|<~31 bound

// ---------- fused prep: x->bf16 cast (bid<4096) + W transposes (bid>=4096) ----
// Wq (z==1) pre-scaled by LOG2E/8 so attention QK^T lands in exp2 domain.
__global__ __launch_bounds__(256) void k_prep(
    const float4* __restrict__ x, ushort4* __restrict__ xb,
    const float* __restrict__ w0, const float* __restrict__ w1,
    const float* __restrict__ w2, const float* __restrict__ w3,
    const float* __restrict__ w4, unsigned short* __restrict__ out) {
  const int bid = blockIdx.x, tid = threadIdx.x;
  if (bid < 4096) {
    const int i = bid * 256 + tid;
    float4 v = x[i];
    ushort4 p;
    p.x = f2bf(v.x); p.y = f2bf(v.y); p.z = f2bf(v.z); p.w = f2bf(v.w);
    xb[i] = p;
    return;
  }
  __shared__ float t[32][33];
  const int tb = bid - 4096;
  const int z = tb >> 10;
  const float* W = (z == 0) ? w0 : (z == 1) ? w1 : (z == 2) ? w2 : (z == 3) ? w3 : w4;
  const float sc = (z == 1) ? (LOG2E / 8.0f) : 1.0f;
  unsigned short* o = out + (size_t)z * (1u << 20);
  const int bx = (tb & 31) * 32, by = ((tb >> 5) & 31) * 32;
  const int tx = tid & 31, ty = tid >> 5;  // 32 x 8
#pragma unroll
  for (int i = 0; i < 4; ++i)
    t[ty + i * 8][tx] = W[(size_t)(by + ty + i * 8) * 1024 + bx + tx];
  __syncthreads();
#pragma unroll
  for (int i = 0; i < 4; ++i)
    o[(size_t)(bx + ty + i * 8) * 1024 + by + tx] = f2bf(t[tx][ty + i * 8] * sc);
}

// ---------- templated NT GEMM core (K=1024): tile (MI*32) x (NI*32) ----------
template <int MI, int NI>
__device__ __forceinline__ void gemm_core_t(const unsigned short* __restrict__ A,
                                            const unsigned short* __restrict__ Bt,
                                            unsigned short* ldsA,
                                            unsigned short* ldsB,
                                            f32x4 acc[MI][NI]) {
  const int tid = threadIdx.x;
  const int w = tid >> 6, lane = tid & 63;
  const int lane15 = lane & 15, quad = lane >> 4;
  const int wm = w >> 1, wn = w & 1;
  for (int ko = 0; ko < 32; ++ko) {
    __syncthreads();
#pragma unroll
    for (int i = 0; i < MI / 2; ++i) {
      const int p = i * 256 + tid;
      async_lds16(A + (p >> 2) * 1024 + ko * 32 + (p & 3) * 8,
                  ldsA + (i * 256 + w * 64) * 8);
    }
#pragma unroll
    for (int i = 0; i < NI / 2; ++i) {
      const int p = i * 256 + tid;
      async_lds16(Bt + (p >> 2) * 1024 + ko * 32 + (p & 3) * 8,
                  ldsB + (i * 256 + w * 64) * 8);
    }
    __syncthreads();
    bf16x8 af[MI], bfr[NI];
#pragma unroll
    for (int t = 0; t < MI; ++t)
      af[t] = *(const bf16x8*)&ldsA[(wm * (MI * 16) + t * 16 + lane15) * 32 + quad * 8];
#pragma unroll
    for (int t = 0; t < NI; ++t)
      bfr[t] = *(const bf16x8*)&ldsB[(wn * (NI * 16) + t * 16 + lane15) * 32 + quad * 8];
#pragma unroll
    for (int mi = 0; mi < MI; ++mi)
#pragma unroll
      for (int ni = 0; ni < NI; ++ni)
        acc[mi][ni] = MFMA(af[mi], bfr[ni], acc[mi][ni]);
  }
}

#define GEMM_PROLOGUE(MI_, NI_)                                      \
  __shared__ unsigned short ldsA[(MI_)*32 * 32];                     \
  __shared__ unsigned short ldsB[(NI_)*32 * 32];                     \
  f32x4 acc[MI_][NI_];                                               \
  {                                                                  \
    f32x4 z_ = {0.f, 0.f, 0.f, 0.f};                                 \
    for (int i_ = 0; i_ < (MI_); ++i_)                               \
      for (int j_ = 0; j_ < (NI_); ++j_) acc[i_][j_] = z_;           \
  }

#define GEMM_EPI_IDX(MI_, NI_)                                       \
  const int tid = threadIdx.x, w = tid >> 6, lane = tid & 63;        \
  const int lane15 = lane & 15, quad = lane >> 4;                    \
  const int wm = w >> 1, wn = w & 1;                                 \
  const int r0 = tm + wm * ((MI_)*16) + quad * 4;                    \
  const int c0 = tn + wn * ((NI_)*16) + lane15;

// z: 0=pre(silu,+bpre) 1=q(Wq prescaled) 2=k -> C^T (A=W,B=x), ushort4 stores.
// z=3 v: C (A=x,B=W) -> ushort4 into vt[d][seq].
// XCD swizzle: xcd = z*2 + seq-half.
__global__ __launch_bounds__(256) void k_gemm_qkvpre(
    const unsigned short* __restrict__ xb, const unsigned short* __restrict__ wt,
    const float* __restrict__ bpre, unsigned short* __restrict__ pre,
    unsigned short* __restrict__ qb, unsigned short* __restrict__ kb,
    unsigned short* __restrict__ vt) {
  const int bid = blockIdx.x;
  const int xcd = bid & 7, idx = bid >> 3;
  const int z = xcd >> 1, half = xcd & 1;
  const int wtile = (idx >> 4) * 128;
  const int stile = half * 2048 + (idx & 15) * 128;
  int tm, tn;
  if (z == 3) { tm = stile; tn = wtile; }
  else        { tm = wtile; tn = stile; }
  const unsigned short* At =
      (z == 3) ? xb + (size_t)tm * 1024
               : wt + (size_t)z * (1u << 20) + (size_t)tm * 1024;
  const unsigned short* Bt_ =
      (z == 3) ? wt + (size_t)3 * (1u << 20) + (size_t)tn * 1024
               : xb + (size_t)tn * 1024;
  GEMM_PROLOGUE(4, 4);
  gemm_core_t<4, 4>(At, Bt_, ldsA, ldsB, acc);
  GEMM_EPI_IDX(4, 4);
  if (z == 0) {
#pragma unroll
    for (int mi = 0; mi < 4; ++mi) {
      const float4 b4 = *(const float4*)&bpre[r0 + mi * 16];
#pragma unroll
      for (int ni = 0; ni < 4; ++ni) {
        const int seq = c0 + ni * 16;
        float vv[4];
#pragma unroll
        for (int rr = 0; rr < 4; ++rr) {
          float v = acc[mi][ni][rr] + ((const float*)&b4)[rr];
          vv[rr] = v / (1.0f + __expf(-v));
        }
        ushort4 pk;
        pk.x = f2bf(vv[0]); pk.y = f2bf(vv[1]);
        pk.z = f2bf(vv[2]); pk.w = f2bf(vv[3]);
        *(ushort4*)&pre[(size_t)seq * 1024 + r0 + mi * 16] = pk;
      }
    }
  } else if (z == 1 || z == 2) {
    unsigned short* dst = (z == 1) ? qb : kb;
#pragma unroll
    for (int mi = 0; mi < 4; ++mi)
#pragma unroll
      for (int ni = 0; ni < 4; ++ni) {
        const int seq = c0 + ni * 16;
        ushort4 pk;
        pk.x = f2bf(acc[mi][ni][0]); pk.y = f2bf(acc[mi][ni][1]);
        pk.z = f2bf(acc[mi][ni][2]); pk.w = f2bf(acc[mi][ni][3]);
        *(ushort4*)&dst[(size_t)seq * 1024 + r0 + mi * 16] = pk;
      }
  } else {
#pragma unroll
    for (int mi = 0; mi < 4; ++mi) {
      const int m = r0 + mi * 16;
      const int bb_ = m >> 10, nseq = m & 1023;
#pragma unroll
      for (int ni = 0; ni < 4; ++ni) {
        const int cg = c0 + ni * 16;
        const int hh = cg >> 6, dd = cg & 63;
        ushort4 pk;
        pk.x = f2bf(acc[mi][ni][0]); pk.y = f2bf(acc[mi][ni][1]);
        pk.z = f2bf(acc[mi][ni][2]); pk.w = f2bf(acc[mi][ni][3]);
        *(ushort4*)&vt[(size_t)(((bb_ * 16 + hh) << 6) + dd) * 1024 + nseq] = pk;
      }
    }
  }
}

// Lg[b][i][j] = (pi*log2e/32) * dot(pre_i, pre_j); symmetric -> store
// lg[col][row] so rr packs into ushort4.
__global__ __launch_bounds__(256) void k_gemm_logits(
    const unsigned short* __restrict__ pre, const float* __restrict__ pi,
    unsigned short* __restrict__ lg) {
  const int bz = blockIdx.z;
  const unsigned short* base = pre + ((size_t)bz << 20);
  const int tm = blockIdx.y * 64, tn = blockIdx.x * 128;
  GEMM_PROLOGUE(2, 4);
  gemm_core_t<2, 4>(base + (size_t)tm * 1024, base + (size_t)tn * 1024, ldsA, ldsB, acc);
  const float sc = pi[0] * (LOG2E / 32.0f);
  GEMM_EPI_IDX(2, 4);
#pragma unroll
  for (int mi = 0; mi < 2; ++mi)
#pragma unroll
    for (int ni = 0; ni < 4; ++ni) {
      const int col = c0 + ni * 16;
      ushort4 pk;
      pk.x = f2bf(acc[mi][ni][0] * sc); pk.y = f2bf(acc[mi][ni][1] * sc);
      pk.z = f2bf(acc[mi][ni][2] * sc); pk.w = f2bf(acc[mi][ni][3] * sc);
      *(ushort4*)&lg[((size_t)bz << 20) + (size_t)col * 1024 + r0 + mi * 16] = pk;
    }
}

// out = ao @ Wproj + bproj + x, computed as C^T -> float4 stores along outdim.
__global__ __launch_bounds__(256) void k_gemm_out(
    const unsigned short* __restrict__ ao, const unsigned short* __restrict__ wtp,
    const float* __restrict__ bproj, const float* __restrict__ xres,
    float* __restrict__ out) {
  const int tm = blockIdx.x * 64, tn = blockIdx.y * 128;
  GEMM_PROLOGUE(2, 4);
  gemm_core_t<2, 4>(wtp + (size_t)tm * 1024, ao + (size_t)tn * 1024, ldsA, ldsB, acc);
  GEMM_EPI_IDX(2, 4);
#pragma unroll
  for (int mi = 0; mi < 2; ++mi) {
    const float4 b4 = *(const float4*)&bproj[r0 + mi * 16];
#pragma unroll
    for (int ni = 0; ni < 4; ++ni) {
      const int seq = c0 + ni * 16;
      const size_t idx = (size_t)seq * 1024 + r0 + mi * 16;
      const float4 rv = *(const float4*)&xres[idx];
      float4 ov;
      ov.x = acc[mi][ni][0] + b4.x + rv.x;
      ov.y = acc[mi][ni][1] + b4.y + rv.y;
      ov.z = acc[mi][ni][2] + b4.z + rv.z;
      ov.w = acc[mi][ni][3] + b4.w + rv.w;
      *(float4*)&out[idx] = ov;
    }
  }
}

// ---------- fused flash attention, S^T = K q^T, fixed-offset softmax -------
// P = exp2(s - SOFT_OFF): scores are bounded (|qk|*log2e <~17, bias <~14), so
// no running max / rescale needed -- removes the per-chunk serial reduce.
// Per-lane l partials accumulate across chunks; single cross-lane reduce at end.
// P aliases ldsK (LDS 32KB); XCD swizzle: xcd = b*2 + h/8.
__global__ __launch_bounds__(256, 5) void k_attn(
    const unsigned short* __restrict__ qb, const unsigned short* __restrict__ kb,
    const unsigned short* __restrict__ vt, const unsigned short* __restrict__ lg,
    unsigned short* __restrict__ ao) {
  __shared__ unsigned short ldsK[128 * 64];  // [kv][d] swz ^(kv&7); then P
  __shared__ unsigned short ldsV[64 * 128];  // [d][kv] swz ^(d&15)
  const int bid = blockIdx.x;
  const int xcd = bid & 7, idx = bid >> 3;
  const int b = xcd >> 1, hg = xcd & 1;
  const int h = hg * 8 + (idx >> 4);
  const int q0 = (idx & 15) * 64;
  const int tid = threadIdx.x, w = tid >> 6, lane = tid & 63;
  const int lane15 = lane & 15, quad = lane >> 4;
  const int qw = q0 + w * 16;
  char* Pb = (char*)(ldsK + w * 2048);  // per-wave 4 KB P region

  bf16x8 qf[2];
  {
    const unsigned short* qrow =
        qb + (size_t)((b << 10) + qw + lane15) * 1024 + (h << 6);
    qf[0] = *(const bf16x8*)(qrow + quad * 8);
    qf[1] = *(const bf16x8*)(qrow + 32 + quad * 8);
  }
  float lcol = 0.f;  // per-lane partial sum of P over this lane's kv rows
  f32x4 o[4];
  {
    f32x4 z_ = {0.f, 0.f, 0.f, 0.f};
#pragma unroll
    for (int nt = 0; nt < 4; ++nt) o[nt] = z_;
  }

  for (int c = 0; c < 8; ++c) {
    const int kv0 = c * 128;
    __syncthreads();  // prev chunk P/V reads complete
#pragma unroll
    for (int i = 0; i < 4; ++i) {
      const int p = i * 256 + tid;
      {
        const int r = p >> 3, cc = (p & 7) ^ (r & 7);
        async_lds16(kb + (size_t)((b << 10) + kv0 + r) * 1024 + (h << 6) + cc * 8,
                    ldsK + (i * 256 + w * 64) * 8);
      }
      {
        const int r = p >> 4, cc = (p & 15) ^ (r & 15);
        async_lds16(vt + (size_t)(((b * 16 + h) << 6) + r) * 1024 + kv0 + cc * 8,
                    ldsV + (i * 256 + w * 64) * 8);
      }
    }
    uint2 lgv[8];
    {
      const unsigned short* lgrow =
          lg + ((size_t)b << 20) + (size_t)(qw + lane15) * 1024 + kv0 + quad * 4;
#pragma unroll
      for (int mi = 0; mi < 8; ++mi) lgv[mi] = *(const uint2*)(lgrow + mi * 16);
    }
    __syncthreads();  // staging visible

    // S^T = K q^T, accumulator seeded with bias
    f32x4 s[8];
#pragma unroll
    for (int mi = 0; mi < 8; ++mi) {
      const int row = mi * 16 + lane15;
      bf16x8 k0 = *(const bf16x8*)&ldsK[row * 64 + ((quad ^ (row & 7)) << 3)];
      bf16x8 k1 = *(const bf16x8*)&ldsK[row * 64 + (((4 + quad) ^ (row & 7)) << 3)];
      f32x4 t;
      t[0] = __uint_as_float(lgv[mi].x << 16);
      t[1] = __uint_as_float(lgv[mi].x & 0xffff0000u);
      t[2] = __uint_as_float(lgv[mi].y << 16);
      t[3] = __uint_as_float(lgv[mi].y & 0xffff0000u);
      t = MFMA(k0, qf[0], t);
      t = MFMA(k1, qf[1], t);
      s[mi] = t;
    }
    // P = exp2(s - OFF), fully parallel; accumulate per-lane l partials
    float rs = 0.f;
    uint2 pk[8];
#pragma unroll
    for (int mi = 0; mi < 8; ++mi) {
      const float p0 = exp2f(s[mi][0] - SOFT_OFF), p1 = exp2f(s[mi][1] - SOFT_OFF);
      const float p2 = exp2f(s[mi][2] - SOFT_OFF), p3 = exp2f(s[mi][3] - SOFT_OFF);
      rs += (p0 + p1) + (p2 + p3);
      pk[mi].x = ((__float_as_uint(p1) + 0x8000u) & 0xffff0000u) |
                 ((__float_as_uint(p0) + 0x8000u) >> 16);
      pk[mi].y = ((__float_as_uint(p3) + 0x8000u) & 0xffff0000u) |
                 ((__float_as_uint(p2) + 0x8000u) >> 16);
    }
    lcol += rs;

    __syncthreads();  // all waves done reading K; P may overwrite it
#pragma unroll
    for (int mi = 0; mi < 8; ++mi)
      *(uint2*)(Pb + lane15 * 256 + (((2 * mi + (quad >> 1)) ^ lane15) << 4) +
                ((quad & 1) << 3)) = pk[mi];
    // O += P V
#pragma unroll
    for (int ks = 0; ks < 4; ++ks) {
      bf16x8 pf = *(const bf16x8*)(Pb + lane15 * 256 +
                                   ((((ks << 2) + quad) ^ lane15) << 4));
#pragma unroll
      for (int nt = 0; nt < 4; ++nt) {
        const int d = nt * 16 + lane15;
        bf16x8 vf = *(const bf16x8*)&ldsV[d * 128 +
                                          (((ks * 4 + quad) ^ (d & 15)) << 3)];
        o[nt] = MFMA(pf, vf, o[nt]);
      }
    }
  }
  // final l reduce (once) + normalize + store [B*N, H*Dh] bf16
  lcol += __shfl_xor(lcol, 16);
  lcol += __shfl_xor(lcol, 32);
  const float rinv = 1.0f / lcol;
  float rv[4];
#pragma unroll
  for (int rr = 0; rr < 4; ++rr) rv[rr] = __shfl(rinv, quad * 4 + rr);
#pragma unroll
  for (int nt = 0; nt < 4; ++nt) {
    const int cg = (h << 6) + nt * 16 + lane15;
#pragma unroll
    for (int rr = 0; rr < 4; ++rr) {
      const int m = (b << 10) + qw + quad * 4 + rr;
      ao[(size_t)m * 1024 + cg] = f2bf(o[nt][rr] * rv[rr]);
    }
  }
}

// ---------- launch ----------
extern "C" void kernel_launch(void* const* d_in, const int* in_sizes, int n_in,
                              void* d_out, int out_size, void* d_ws, size_t ws_size,
                              hipStream_t stream) {
  const float* x     = (const float*)d_in[0];
  const float* Wq    = (const float*)d_in[1];
  const float* Wk    = (const float*)d_in[2];
  const float* Wv    = (const float*)d_in[3];
  const float* Wproj = (const float*)d_in[4];
  const float* bproj = (const float*)d_in[5];
  const float* Wpre  = (const float*)d_in[6];
  const float* bpre  = (const float*)d_in[7];
  const float* pi    = (const float*)d_in[8];
  float* out = (float*)d_out;
  char* ws = (char*)d_ws;

  unsigned short* xb  = (unsigned short*)(ws);               // 8 MB (later: lg)
  unsigned short* wt  = (unsigned short*)(ws + (8u << 20));  // 10 MB
  unsigned short* pre = (unsigned short*)(ws + (18u << 20)); // 8 MB (later: ao)
  unsigned short* qb  = (unsigned short*)(ws + (26u << 20)); // 8 MB
  unsigned short* kb  = (unsigned short*)(ws + (34u << 20)); // 8 MB
  unsigned short* vt  = (unsigned short*)(ws + (42u << 20)); // 8 MB
  unsigned short* lg  = xb;   // xb dead after k_gemm_qkvpre
  unsigned short* ao  = pre;  // pre dead after k_gemm_logits

  k_prep<<<dim3(4096 + 5120), dim3(256), 0, stream>>>(
      (const float4*)x, (ushort4*)xb, Wpre, Wq, Wk, Wv, Wproj, wt);
  k_gemm_qkvpre<<<dim3(1024), dim3(256), 0, stream>>>(xb, wt, bpre, pre, qb, kb, vt);
  k_gemm_logits<<<dim3(8, 16, 4), dim3(256), 0, stream>>>(pre, pi, lg);
  k_attn<<<dim3(1024), dim3(256), 0, stream>>>(qb, kb, vt, lg, ao);
  k_gemm_out<<<dim3(16, 32, 1), dim3(256), 0, stream>>>(ao, wt + 4 * (1u << 20), bproj, x, out);
}

// Round 6
// 242.764 us; speedup vs baseline: 1.1549x; 1.0580x over previous
//
#include <hip/hip_runtime.h>

// ---------- types ----------
using bf16x8 = __attribute__((ext_vector_type(8))) short;
using v8bf   = __attribute__((ext_vector_type(8))) __bf16;
using f32x4  = __attribute__((ext_vector_type(4))) float;

typedef const __attribute__((address_space(1))) void GASV;
typedef __attribute__((address_space(3))) void LASV;

template <typename V>
__device__ __forceinline__ auto mfma_bf16_impl(V a, V b, f32x4 c, int)
    -> decltype(__builtin_amdgcn_mfma_f32_16x16x32_bf16(a, b, c, 0, 0, 0)) {
  return __builtin_amdgcn_mfma_f32_16x16x32_bf16(a, b, c, 0, 0, 0);
}
template <typename V>
__device__ __forceinline__ f32x4 mfma_bf16_impl(V a, V b, f32x4 c, long) {
  return __builtin_amdgcn_mfma_f32_16x16x32_bf16(
      __builtin_bit_cast(v8bf, a), __builtin_bit_cast(v8bf, b), c, 0, 0, 0);
}
__device__ __forceinline__ f32x4 MFMA(bf16x8 a, bf16x8 b, f32x4 c) {
  return mfma_bf16_impl(a, b, c, 0);
}

__device__ __forceinline__ void async_lds16(const void* g, void* l) {
  __builtin_amdgcn_global_load_lds((GASV*)g, (LASV*)l, 16, 0, 0);
}

__device__ __forceinline__ unsigned short f2bf(float x) {
  unsigned u = __float_as_uint(x);
  u = u + 0x7fffu + ((u >> 16) & 1u);
  return (unsigned short)(u >> 16);
}

#define LOG2E 1.4426950408889634f
#define SOFT_OFF 14.0f  // fixed softmax offset (exp2 domain)

// ---------- fused prep: x->bf16 cast (bid<4096) + W transposes (bid>=4096) ----
// Wq (z==1) pre-scaled by LOG2E/8 so attention QK^T lands in exp2 domain.
__global__ __launch_bounds__(256) void k_prep(
    const float4* __restrict__ x, ushort4* __restrict__ xb,
    const float* __restrict__ w0, const float* __restrict__ w1,
    const float* __restrict__ w2, const float* __restrict__ w3,
    const float* __restrict__ w4, unsigned short* __restrict__ out) {
  const int bid = blockIdx.x, tid = threadIdx.x;
  if (bid < 4096) {
    const int i = bid * 256 + tid;
    float4 v = x[i];
    ushort4 p;
    p.x = f2bf(v.x); p.y = f2bf(v.y); p.z = f2bf(v.z); p.w = f2bf(v.w);
    xb[i] = p;
    return;
  }
  __shared__ float t[32][33];
  const int tb = bid - 4096;
  const int z = tb >> 10;
  const float* W = (z == 0) ? w0 : (z == 1) ? w1 : (z == 2) ? w2 : (z == 3) ? w3 : w4;
  const float sc = (z == 1) ? (LOG2E / 8.0f) : 1.0f;
  unsigned short* o = out + (size_t)z * (1u << 20);
  const int bx = (tb & 31) * 32, by = ((tb >> 5) & 31) * 32;
  const int tx = tid & 31, ty = tid >> 5;  // 32 x 8
#pragma unroll
  for (int i = 0; i < 4; ++i)
    t[ty + i * 8][tx] = W[(size_t)(by + ty + i * 8) * 1024 + bx + tx];
  __syncthreads();
#pragma unroll
  for (int i = 0; i < 4; ++i)
    o[(size_t)(bx + ty + i * 8) * 1024 + by + tx] = f2bf(t[tx][ty + i * 8] * sc);
}

// ---------- templated NT GEMM core, BK=64 (K=1024): tile (MI*32)x(NI*32) ----
// 32 MFMAs per barrier pair (2x the m97 cadence); rows are 128 B so the 16 B
// chunk index is XOR-swizzled with (row&7) to keep ds_read_b128 at the free
// 2-way bank aliasing (same pattern as k_attn's ldsK).
template <int MI, int NI>
__device__ __forceinline__ void gemm_core_t(const unsigned short* __restrict__ A,
                                            const unsigned short* __restrict__ Bt,
                                            unsigned short* ldsA,
                                            unsigned short* ldsB,
                                            f32x4 acc[MI][NI]) {
  const int tid = threadIdx.x;
  const int w = tid >> 6, lane = tid & 63;
  const int lane15 = lane & 15, quad = lane >> 4;
  const int wm = w >> 1, wn = w & 1;
  for (int ko = 0; ko < 16; ++ko) {
    __syncthreads();
#pragma unroll
    for (int i = 0; i < MI; ++i) {
      const int p = i * 256 + tid;
      const int r = p >> 3, cc = (p & 7) ^ (r & 7);
      async_lds16(A + r * 1024 + ko * 64 + cc * 8, ldsA + (i * 256 + w * 64) * 8);
    }
#pragma unroll
    for (int i = 0; i < NI; ++i) {
      const int p = i * 256 + tid;
      const int r = p >> 3, cc = (p & 7) ^ (r & 7);
      async_lds16(Bt + r * 1024 + ko * 64 + cc * 8, ldsB + (i * 256 + w * 64) * 8);
    }
    __syncthreads();
    bf16x8 af[MI][2], bfr[NI][2];
#pragma unroll
    for (int t = 0; t < MI; ++t) {
      const int row = wm * (MI * 16) + t * 16 + lane15;
#pragma unroll
      for (int h = 0; h < 2; ++h)
        af[t][h] = *(const bf16x8*)&ldsA[row * 64 + (((h * 4 + quad) ^ (row & 7)) << 3)];
    }
#pragma unroll
    for (int t = 0; t < NI; ++t) {
      const int row = wn * (NI * 16) + t * 16 + lane15;
#pragma unroll
      for (int h = 0; h < 2; ++h)
        bfr[t][h] = *(const bf16x8*)&ldsB[row * 64 + (((h * 4 + quad) ^ (row & 7)) << 3)];
    }
#pragma unroll
    for (int mi = 0; mi < MI; ++mi)
#pragma unroll
      for (int ni = 0; ni < NI; ++ni) {
        acc[mi][ni] = MFMA(af[mi][0], bfr[ni][0], acc[mi][ni]);
        acc[mi][ni] = MFMA(af[mi][1], bfr[ni][1], acc[mi][ni]);
      }
  }
}

#define GEMM_PROLOGUE(MI_, NI_)                                      \
  __shared__ unsigned short ldsA[(MI_)*32 * 64];                     \
  __shared__ unsigned short ldsB[(NI_)*32 * 64];                     \
  f32x4 acc[MI_][NI_];                                               \
  {                                                                  \
    f32x4 z_ = {0.f, 0.f, 0.f, 0.f};                                 \
    for (int i_ = 0; i_ < (MI_); ++i_)                               \
      for (int j_ = 0; j_ < (NI_); ++j_) acc[i_][j_] = z_;           \
  }

#define GEMM_EPI_IDX(MI_, NI_)                                       \
  const int tid = threadIdx.x, w = tid >> 6, lane = tid & 63;        \
  const int lane15 = lane & 15, quad = lane >> 4;                    \
  const int wm = w >> 1, wn = w & 1;                                 \
  const int r0 = tm + wm * ((MI_)*16) + quad * 4;                    \
  const int c0 = tn + wn * ((NI_)*16) + lane15;

// z: 0=pre(silu,+bpre) 1=q(Wq prescaled) 2=k -> C^T (A=W,B=x), ushort4 stores.
// z=3 v: C (A=x,B=W) -> ushort4 into vt[d][seq].
// XCD swizzle: xcd = z*2 + seq-half.
__global__ __launch_bounds__(256) void k_gemm_qkvpre(
    const unsigned short* __restrict__ xb, const unsigned short* __restrict__ wt,
    const float* __restrict__ bpre, unsigned short* __restrict__ pre,
    unsigned short* __restrict__ qb, unsigned short* __restrict__ kb,
    unsigned short* __restrict__ vt) {
  const int bid = blockIdx.x;
  const int xcd = bid & 7, idx = bid >> 3;
  const int z = xcd >> 1, half = xcd & 1;
  const int wtile = (idx >> 4) * 128;
  const int stile = half * 2048 + (idx & 15) * 128;
  int tm, tn;
  if (z == 3) { tm = stile; tn = wtile; }
  else        { tm = wtile; tn = stile; }
  const unsigned short* At =
      (z == 3) ? xb + (size_t)tm * 1024
               : wt + (size_t)z * (1u << 20) + (size_t)tm * 1024;
  const unsigned short* Bt_ =
      (z == 3) ? wt + (size_t)3 * (1u << 20) + (size_t)tn * 1024
               : xb + (size_t)tn * 1024;
  GEMM_PROLOGUE(4, 4);
  gemm_core_t<4, 4>(At, Bt_, ldsA, ldsB, acc);
  GEMM_EPI_IDX(4, 4);
  if (z == 0) {
#pragma unroll
    for (int mi = 0; mi < 4; ++mi) {
      const float4 b4 = *(const float4*)&bpre[r0 + mi * 16];
#pragma unroll
      for (int ni = 0; ni < 4; ++ni) {
        const int seq = c0 + ni * 16;
        float vv[4];
#pragma unroll
        for (int rr = 0; rr < 4; ++rr) {
          float v = acc[mi][ni][rr] + ((const float*)&b4)[rr];
          vv[rr] = v / (1.0f + __expf(-v));
        }
        ushort4 pk;
        pk.x = f2bf(vv[0]); pk.y = f2bf(vv[1]);
        pk.z = f2bf(vv[2]); pk.w = f2bf(vv[3]);
        *(ushort4*)&pre[(size_t)seq * 1024 + r0 + mi * 16] = pk;
      }
    }
  } else if (z == 1 || z == 2) {
    unsigned short* dst = (z == 1) ? qb : kb;
#pragma unroll
    for (int mi = 0; mi < 4; ++mi)
#pragma unroll
      for (int ni = 0; ni < 4; ++ni) {
        const int seq = c0 + ni * 16;
        ushort4 pk;
        pk.x = f2bf(acc[mi][ni][0]); pk.y = f2bf(acc[mi][ni][1]);
        pk.z = f2bf(acc[mi][ni][2]); pk.w = f2bf(acc[mi][ni][3]);
        *(ushort4*)&dst[(size_t)seq * 1024 + r0 + mi * 16] = pk;
      }
  } else {
#pragma unroll
    for (int mi = 0; mi < 4; ++mi) {
      const int m = r0 + mi * 16;
      const int bb_ = m >> 10, nseq = m & 1023;
#pragma unroll
      for (int ni = 0; ni < 4; ++ni) {
        const int cg = c0 + ni * 16;
        const int hh = cg >> 6, dd = cg & 63;
        ushort4 pk;
        pk.x = f2bf(acc[mi][ni][0]); pk.y = f2bf(acc[mi][ni][1]);
        pk.z = f2bf(acc[mi][ni][2]); pk.w = f2bf(acc[mi][ni][3]);
        *(ushort4*)&vt[(size_t)(((bb_ * 16 + hh) << 6) + dd) * 1024 + nseq] = pk;
      }
    }
  }
}

// Lg[b][i][j] = (pi*log2e/32) * dot(pre_i, pre_j); symmetric -> store
// lg[col][row] so rr packs into ushort4.
__global__ __launch_bounds__(256) void k_gemm_logits(
    const unsigned short* __restrict__ pre, const float* __restrict__ pi,
    unsigned short* __restrict__ lg) {
  const int bz = blockIdx.z;
  const unsigned short* base = pre + ((size_t)bz << 20);
  const int tm = blockIdx.y * 64, tn = blockIdx.x * 128;
  GEMM_PROLOGUE(2, 4);
  gemm_core_t<2, 4>(base + (size_t)tm * 1024, base + (size_t)tn * 1024, ldsA, ldsB, acc);
  const float sc = pi[0] * (LOG2E / 32.0f);
  GEMM_EPI_IDX(2, 4);
#pragma unroll
  for (int mi = 0; mi < 2; ++mi)
#pragma unroll
    for (int ni = 0; ni < 4; ++ni) {
      const int col = c0 + ni * 16;
      ushort4 pk;
      pk.x = f2bf(acc[mi][ni][0] * sc); pk.y = f2bf(acc[mi][ni][1] * sc);
      pk.z = f2bf(acc[mi][ni][2] * sc); pk.w = f2bf(acc[mi][ni][3] * sc);
      *(ushort4*)&lg[((size_t)bz << 20) + (size_t)col * 1024 + r0 + mi * 16] = pk;
    }
}

// out = ao @ Wproj + bproj + x, computed as C^T -> float4 stores along outdim.
__global__ __launch_bounds__(256) void k_gemm_out(
    const unsigned short* __restrict__ ao, const unsigned short* __restrict__ wtp,
    const float* __restrict__ bproj, const float* __restrict__ xres,
    float* __restrict__ out) {
  const int tm = blockIdx.x * 64, tn = blockIdx.y * 128;
  GEMM_PROLOGUE(2, 4);
  gemm_core_t<2, 4>(wtp + (size_t)tm * 1024, ao + (size_t)tn * 1024, ldsA, ldsB, acc);
  GEMM_EPI_IDX(2, 4);
#pragma unroll
  for (int mi = 0; mi < 2; ++mi) {
    const float4 b4 = *(const float4*)&bproj[r0 + mi * 16];
#pragma unroll
    for (int ni = 0; ni < 4; ++ni) {
      const int seq = c0 + ni * 16;
      const size_t idx = (size_t)seq * 1024 + r0 + mi * 16;
      const float4 rv = *(const float4*)&xres[idx];
      float4 ov;
      ov.x = acc[mi][ni][0] + b4.x + rv.x;
      ov.y = acc[mi][ni][1] + b4.y + rv.y;
      ov.z = acc[mi][ni][2] + b4.z + rv.z;
      ov.w = acc[mi][ni][3] + b4.w + rv.w;
      *(float4*)&out[idx] = ov;
    }
  }
}

// ---------- fused flash attention, S^T = K q^T, fixed-offset softmax -------
// P = exp2(s - SOFT_OFF); per-lane l partials, one reduce at end.
// P aliases ldsK (LDS 32KB); XCD swizzle: xcd = b*2 + h/8.
__global__ __launch_bounds__(256, 5) void k_attn(
    const unsigned short* __restrict__ qb, const unsigned short* __restrict__ kb,
    const unsigned short* __restrict__ vt, const unsigned short* __restrict__ lg,
    unsigned short* __restrict__ ao) {
  __shared__ unsigned short ldsK[128 * 64];  // [kv][d] swz ^(kv&7); then P
  __shared__ unsigned short ldsV[64 * 128];  // [d][kv] swz ^(d&15)
  const int bid = blockIdx.x;
  const int xcd = bid & 7, idx = bid >> 3;
  const int b = xcd >> 1, hg = xcd & 1;
  const int h = hg * 8 + (idx >> 4);
  const int q0 = (idx & 15) * 64;
  const int tid = threadIdx.x, w = tid >> 6, lane = tid & 63;
  const int lane15 = lane & 15, quad = lane >> 4;
  const int qw = q0 + w * 16;
  char* Pb = (char*)(ldsK + w * 2048);  // per-wave 4 KB P region

  bf16x8 qf[2];
  {
    const unsigned short* qrow =
        qb + (size_t)((b << 10) + qw + lane15) * 1024 + (h << 6);
    qf[0] = *(const bf16x8*)(qrow + quad * 8);
    qf[1] = *(const bf16x8*)(qrow + 32 + quad * 8);
  }
  float lcol = 0.f;
  f32x4 o[4];
  {
    f32x4 z_ = {0.f, 0.f, 0.f, 0.f};
#pragma unroll
    for (int nt = 0; nt < 4; ++nt) o[nt] = z_;
  }

  for (int c = 0; c < 8; ++c) {
    const int kv0 = c * 128;
    __syncthreads();  // prev chunk P/V reads complete
#pragma unroll
    for (int i = 0; i < 4; ++i) {
      const int p = i * 256 + tid;
      {
        const int r = p >> 3, cc = (p & 7) ^ (r & 7);
        async_lds16(kb + (size_t)((b << 10) + kv0 + r) * 1024 + (h << 6) + cc * 8,
                    ldsK + (i * 256 + w * 64) * 8);
      }
      {
        const int r = p >> 4, cc = (p & 15) ^ (r & 15);
        async_lds16(vt + (size_t)(((b * 16 + h) << 6) + r) * 1024 + kv0 + cc * 8,
                    ldsV + (i * 256 + w * 64) * 8);
      }
    }
    uint2 lgv[8];
    {
      const unsigned short* lgrow =
          lg + ((size_t)b << 20) + (size_t)(qw + lane15) * 1024 + kv0 + quad * 4;
#pragma unroll
      for (int mi = 0; mi < 8; ++mi) lgv[mi] = *(const uint2*)(lgrow + mi * 16);
    }
    __syncthreads();  // staging visible

    // S^T = K q^T, accumulator seeded with bias
    f32x4 s[8];
#pragma unroll
    for (int mi = 0; mi < 8; ++mi) {
      const int row = mi * 16 + lane15;
      bf16x8 k0 = *(const bf16x8*)&ldsK[row * 64 + ((quad ^ (row & 7)) << 3)];
      bf16x8 k1 = *(const bf16x8*)&ldsK[row * 64 + (((4 + quad) ^ (row & 7)) << 3)];
      f32x4 t;
      t[0] = __uint_as_float(lgv[mi].x << 16);
      t[1] = __uint_as_float(lgv[mi].x & 0xffff0000u);
      t[2] = __uint_as_float(lgv[mi].y << 16);
      t[3] = __uint_as_float(lgv[mi].y & 0xffff0000u);
      t = MFMA(k0, qf[0], t);
      t = MFMA(k1, qf[1], t);
      s[mi] = t;
    }
    // P = exp2(s - OFF), fully parallel; per-lane l partials
    float rs = 0.f;
    uint2 pk[8];
#pragma unroll
    for (int mi = 0; mi < 8; ++mi) {
      const float p0 = exp2f(s[mi][0] - SOFT_OFF), p1 = exp2f(s[mi][1] - SOFT_OFF);
      const float p2 = exp2f(s[mi][2] - SOFT_OFF), p3 = exp2f(s[mi][3] - SOFT_OFF);
      rs += (p0 + p1) + (p2 + p3);
      pk[mi].x = ((__float_as_uint(p1) + 0x8000u) & 0xffff0000u) |
                 ((__float_as_uint(p0) + 0x8000u) >> 16);
      pk[mi].y = ((__float_as_uint(p3) + 0x8000u) & 0xffff0000u) |
                 ((__float_as_uint(p2) + 0x8000u) >> 16);
    }
    lcol += rs;

    __syncthreads();  // all waves done reading K; P may overwrite it
#pragma unroll
    for (int mi = 0; mi < 8; ++mi)
      *(uint2*)(Pb + lane15 * 256 + (((2 * mi + (quad >> 1)) ^ lane15) << 4) +
                ((quad & 1) << 3)) = pk[mi];
    // O += P V
#pragma unroll
    for (int ks = 0; ks < 4; ++ks) {
      bf16x8 pf = *(const bf16x8*)(Pb + lane15 * 256 +
                                   ((((ks << 2) + quad) ^ lane15) << 4));
#pragma unroll
      for (int nt = 0; nt < 4; ++nt) {
        const int d = nt * 16 + lane15;
        bf16x8 vf = *(const bf16x8*)&ldsV[d * 128 +
                                          (((ks * 4 + quad) ^ (d & 15)) << 3)];
        o[nt] = MFMA(pf, vf, o[nt]);
      }
    }
  }
  // final l reduce + normalize + store [B*N, H*Dh] bf16
  lcol += __shfl_xor(lcol, 16);
  lcol += __shfl_xor(lcol, 32);
  const float rinv = 1.0f / lcol;
  float rv[4];
#pragma unroll
  for (int rr = 0; rr < 4; ++rr) rv[rr] = __shfl(rinv, quad * 4 + rr);
#pragma unroll
  for (int nt = 0; nt < 4; ++nt) {
    const int cg = (h << 6) + nt * 16 + lane15;
#pragma unroll
    for (int rr = 0; rr < 4; ++rr) {
      const int m = (b << 10) + qw + quad * 4 + rr;
      ao[(size_t)m * 1024 + cg] = f2bf(o[nt][rr] * rv[rr]);
    }
  }
}

// ---------- launch ----------
extern "C" void kernel_launch(void* const* d_in, const int* in_sizes, int n_in,
                              void* d_out, int out_size, void* d_ws, size_t ws_size,
                              hipStream_t stream) {
  const float* x     = (const float*)d_in[0];
  const float* Wq    = (const float*)d_in[1];
  const float* Wk    = (const float*)d_in[2];
  const float* Wv    = (const float*)d_in[3];
  const float* Wproj = (const float*)d_in[4];
  const float* bproj = (const float*)d_in[5];
  const float* Wpre  = (const float*)d_in[6];
  const float* bpre  = (const float*)d_in[7];
  const float* pi    = (const float*)d_in[8];
  float* out = (float*)d_out;
  char* ws = (char*)d_ws;

  unsigned short* xb  = (unsigned short*)(ws);               // 8 MB (later: lg)
  unsigned short* wt  = (unsigned short*)(ws + (8u << 20));  // 10 MB
  unsigned short* pre = (unsigned short*)(ws + (18u << 20)); // 8 MB (later: ao)
  unsigned short* qb  = (unsigned short*)(ws + (26u << 20)); // 8 MB
  unsigned short* kb  = (unsigned short*)(ws + (34u << 20)); // 8 MB
  unsigned short* vt  = (unsigned short*)(ws + (42u << 20)); // 8 MB
  unsigned short* lg  = xb;   // xb dead after k_gemm_qkvpre
  unsigned short* ao  = pre;  // pre dead after k_gemm_logits

  k_prep<<<dim3(4096 + 5120), dim3(256), 0, stream>>>(
      (const float4*)x, (ushort4*)xb, Wpre, Wq, Wk, Wv, Wproj, wt);
  k_gemm_qkvpre<<<dim3(1024), dim3(256), 0, stream>>>(xb, wt, bpre, pre, qb, kb, vt);
  k_gemm_logits<<<dim3(8, 16, 4), dim3(256), 0, stream>>>(pre, pi, lg);
  k_attn<<<dim3(1024), dim3(256), 0, stream>>>(qb, kb, vt, lg, ao);
  k_gemm_out<<<dim3(16, 32, 1), dim3(256), 0, stream>>>(ao, wt + 4 * (1u << 20), bproj, x, out);
}

// Round 7
// 235.284 us; speedup vs baseline: 1.1916x; 1.0318x over previous
//
#include <hip/hip_runtime.h>

// ---------- types ----------
using bf16x8 = __attribute__((ext_vector_type(8))) short;
using v8bf   = __attribute__((ext_vector_type(8))) __bf16;
using f32x4  = __attribute__((ext_vector_type(4))) float;

typedef const __attribute__((address_space(1))) void GASV;
typedef __attribute__((address_space(3))) void LASV;

template <typename V>
__device__ __forceinline__ auto mfma_bf16_impl(V a, V b, f32x4 c, int)
    -> decltype(__builtin_amdgcn_mfma_f32_16x16x32_bf16(a, b, c, 0, 0, 0)) {
  return __builtin_amdgcn_mfma_f32_16x16x32_bf16(a, b, c, 0, 0, 0);
}
template <typename V>
__device__ __forceinline__ f32x4 mfma_bf16_impl(V a, V b, f32x4 c, long) {
  return __builtin_amdgcn_mfma_f32_16x16x32_bf16(
      __builtin_bit_cast(v8bf, a), __builtin_bit_cast(v8bf, b), c, 0, 0, 0);
}
__device__ __forceinline__ f32x4 MFMA(bf16x8 a, bf16x8 b, f32x4 c) {
  return mfma_bf16_impl(a, b, c, 0);
}

__device__ __forceinline__ void async_lds16(const void* g, void* l) {
  __builtin_amdgcn_global_load_lds((GASV*)g, (LASV*)l, 16, 0, 0);
}

__device__ __forceinline__ unsigned short f2bf(float x) {
  unsigned u = __float_as_uint(x);
  u = u + 0x7fffu + ((u >> 16) & 1u);
  return (unsigned short)(u >> 16);
}

#define LOG2E 1.4426950408889634f
#define SOFT_OFF 14.0f  // fixed softmax offset (exp2 domain)

// ---------- fused prep: x->bf16 cast (bid<4096) + W transposes (bid>=4096) ----
// Wq (z==1) pre-scaled by LOG2E/8 so attention QK^T lands in exp2 domain.
__global__ __launch_bounds__(256) void k_prep(
    const float4* __restrict__ x, ushort4* __restrict__ xb,
    const float* __restrict__ w0, const float* __restrict__ w1,
    const float* __restrict__ w2, const float* __restrict__ w3,
    const float* __restrict__ w4, unsigned short* __restrict__ out) {
  const int bid = blockIdx.x, tid = threadIdx.x;
  if (bid < 4096) {
    const int i = bid * 256 + tid;
    float4 v = x[i];
    ushort4 p;
    p.x = f2bf(v.x); p.y = f2bf(v.y); p.z = f2bf(v.z); p.w = f2bf(v.w);
    xb[i] = p;
    return;
  }
  __shared__ float t[32][33];
  const int tb = bid - 4096;
  const int z = tb >> 10;
  const float* W = (z == 0) ? w0 : (z == 1) ? w1 : (z == 2) ? w2 : (z == 3) ? w3 : w4;
  const float sc = (z == 1) ? (LOG2E / 8.0f) : 1.0f;
  unsigned short* o = out + (size_t)z * (1u << 20);
  const int bx = (tb & 31) * 32, by = ((tb >> 5) & 31) * 32;
  const int tx = tid & 31, ty = tid >> 5;  // 32 x 8
#pragma unroll
  for (int i = 0; i < 4; ++i)
    t[ty + i * 8][tx] = W[(size_t)(by + ty + i * 8) * 1024 + bx + tx];
  __syncthreads();
#pragma unroll
  for (int i = 0; i < 4; ++i)
    o[(size_t)(bx + ty + i * 8) * 1024 + by + tx] = f2bf(t[tx][ty + i * 8] * sc);
}

// ---------- templated NT GEMM core, BK=64 (K=1024): tile (MI*32)x(NI*32) ----
// 32 MFMAs per barrier pair; 128B rows, 16B chunk XOR-swizzled with row&7.
template <int MI, int NI>
__device__ __forceinline__ void gemm_core_t(const unsigned short* __restrict__ A,
                                            const unsigned short* __restrict__ Bt,
                                            unsigned short* ldsA,
                                            unsigned short* ldsB,
                                            f32x4 acc[MI][NI]) {
  const int tid = threadIdx.x;
  const int w = tid >> 6, lane = tid & 63;
  const int lane15 = lane & 15, quad = lane >> 4;
  const int wm = w >> 1, wn = w & 1;
  for (int ko = 0; ko < 16; ++ko) {
    __syncthreads();
#pragma unroll
    for (int i = 0; i < MI; ++i) {
      const int p = i * 256 + tid;
      const int r = p >> 3, cc = (p & 7) ^ (r & 7);
      async_lds16(A + r * 1024 + ko * 64 + cc * 8, ldsA + (i * 256 + w * 64) * 8);
    }
#pragma unroll
    for (int i = 0; i < NI; ++i) {
      const int p = i * 256 + tid;
      const int r = p >> 3, cc = (p & 7) ^ (r & 7);
      async_lds16(Bt + r * 1024 + ko * 64 + cc * 8, ldsB + (i * 256 + w * 64) * 8);
    }
    __syncthreads();
    bf16x8 af[MI][2], bfr[NI][2];
#pragma unroll
    for (int t = 0; t < MI; ++t) {
      const int row = wm * (MI * 16) + t * 16 + lane15;
#pragma unroll
      for (int h = 0; h < 2; ++h)
        af[t][h] = *(const bf16x8*)&ldsA[row * 64 + (((h * 4 + quad) ^ (row & 7)) << 3)];
    }
#pragma unroll
    for (int t = 0; t < NI; ++t) {
      const int row = wn * (NI * 16) + t * 16 + lane15;
#pragma unroll
      for (int h = 0; h < 2; ++h)
        bfr[t][h] = *(const bf16x8*)&ldsB[row * 64 + (((h * 4 + quad) ^ (row & 7)) << 3)];
    }
#pragma unroll
    for (int mi = 0; mi < MI; ++mi)
#pragma unroll
      for (int ni = 0; ni < NI; ++ni) {
        acc[mi][ni] = MFMA(af[mi][0], bfr[ni][0], acc[mi][ni]);
        acc[mi][ni] = MFMA(af[mi][1], bfr[ni][1], acc[mi][ni]);
      }
  }
}

#define GEMM_PROLOGUE(MI_, NI_)                                      \
  __shared__ unsigned short ldsA[(MI_)*32 * 64];                     \
  __shared__ unsigned short ldsB[(NI_)*32 * 64];                     \
  f32x4 acc[MI_][NI_];                                               \
  {                                                                  \
    f32x4 z_ = {0.f, 0.f, 0.f, 0.f};                                 \
    for (int i_ = 0; i_ < (MI_); ++i_)                               \
      for (int j_ = 0; j_ < (NI_); ++j_) acc[i_][j_] = z_;           \
  }

#define GEMM_EPI_IDX(MI_, NI_)                                       \
  const int tid = threadIdx.x, w = tid >> 6, lane = tid & 63;        \
  const int lane15 = lane & 15, quad = lane >> 4;                    \
  const int wm = w >> 1, wn = w & 1;                                 \
  const int r0 = tm + wm * ((MI_)*16) + quad * 4;                    \
  const int c0 = tn + wn * ((NI_)*16) + lane15;

// z: 0=pre(silu,+bpre) 1=q(Wq prescaled) 2=k -> C^T (A=W,B=x), ushort4 stores.
// z=3 v: C (A=x,B=W) -> ushort4 into vt[d][seq].
// XCD swizzle: xcd = z*2 + seq-half.
__global__ __launch_bounds__(256) void k_gemm_qkvpre(
    const unsigned short* __restrict__ xb, const unsigned short* __restrict__ wt,
    const float* __restrict__ bpre, unsigned short* __restrict__ pre,
    unsigned short* __restrict__ qb, unsigned short* __restrict__ kb,
    unsigned short* __restrict__ vt) {
  const int bid = blockIdx.x;
  const int xcd = bid & 7, idx = bid >> 3;
  const int z = xcd >> 1, half = xcd & 1;
  const int wtile = (idx >> 4) * 128;
  const int stile = half * 2048 + (idx & 15) * 128;
  int tm, tn;
  if (z == 3) { tm = stile; tn = wtile; }
  else        { tm = wtile; tn = stile; }
  const unsigned short* At =
      (z == 3) ? xb + (size_t)tm * 1024
               : wt + (size_t)z * (1u << 20) + (size_t)tm * 1024;
  const unsigned short* Bt_ =
      (z == 3) ? wt + (size_t)3 * (1u << 20) + (size_t)tn * 1024
               : xb + (size_t)tn * 1024;
  GEMM_PROLOGUE(4, 4);
  gemm_core_t<4, 4>(At, Bt_, ldsA, ldsB, acc);
  GEMM_EPI_IDX(4, 4);
  if (z == 0) {
#pragma unroll
    for (int mi = 0; mi < 4; ++mi) {
      const float4 b4 = *(const float4*)&bpre[r0 + mi * 16];
#pragma unroll
      for (int ni = 0; ni < 4; ++ni) {
        const int seq = c0 + ni * 16;
        float vv[4];
#pragma unroll
        for (int rr = 0; rr < 4; ++rr) {
          float v = acc[mi][ni][rr] + ((const float*)&b4)[rr];
          vv[rr] = v / (1.0f + __expf(-v));
        }
        ushort4 pk;
        pk.x = f2bf(vv[0]); pk.y = f2bf(vv[1]);
        pk.z = f2bf(vv[2]); pk.w = f2bf(vv[3]);
        *(ushort4*)&pre[(size_t)seq * 1024 + r0 + mi * 16] = pk;
      }
    }
  } else if (z == 1 || z == 2) {
    unsigned short* dst = (z == 1) ? qb : kb;
#pragma unroll
    for (int mi = 0; mi < 4; ++mi)
#pragma unroll
      for (int ni = 0; ni < 4; ++ni) {
        const int seq = c0 + ni * 16;
        ushort4 pk;
        pk.x = f2bf(acc[mi][ni][0]); pk.y = f2bf(acc[mi][ni][1]);
        pk.z = f2bf(acc[mi][ni][2]); pk.w = f2bf(acc[mi][ni][3]);
        *(ushort4*)&dst[(size_t)seq * 1024 + r0 + mi * 16] = pk;
      }
  } else {
#pragma unroll
    for (int mi = 0; mi < 4; ++mi) {
      const int m = r0 + mi * 16;
      const int bb_ = m >> 10, nseq = m & 1023;
#pragma unroll
      for (int ni = 0; ni < 4; ++ni) {
        const int cg = c0 + ni * 16;
        const int hh = cg >> 6, dd = cg & 63;
        ushort4 pk;
        pk.x = f2bf(acc[mi][ni][0]); pk.y = f2bf(acc[mi][ni][1]);
        pk.z = f2bf(acc[mi][ni][2]); pk.w = f2bf(acc[mi][ni][3]);
        *(ushort4*)&vt[(size_t)(((bb_ * 16 + hh) << 6) + dd) * 1024 + nseq] = pk;
      }
    }
  }
}

// Lg[b][i][j] = (pi*log2e/32) * dot(pre_i, pre_j); symmetric -> store
// lg[col][row] so rr packs into ushort4.
__global__ __launch_bounds__(256) void k_gemm_logits(
    const unsigned short* __restrict__ pre, const float* __restrict__ pi,
    unsigned short* __restrict__ lg) {
  const int bz = blockIdx.z;
  const unsigned short* base = pre + ((size_t)bz << 20);
  const int tm = blockIdx.y * 64, tn = blockIdx.x * 128;
  GEMM_PROLOGUE(2, 4);
  gemm_core_t<2, 4>(base + (size_t)tm * 1024, base + (size_t)tn * 1024, ldsA, ldsB, acc);
  const float sc = pi[0] * (LOG2E / 32.0f);
  GEMM_EPI_IDX(2, 4);
#pragma unroll
  for (int mi = 0; mi < 2; ++mi)
#pragma unroll
    for (int ni = 0; ni < 4; ++ni) {
      const int col = c0 + ni * 16;
      ushort4 pk;
      pk.x = f2bf(acc[mi][ni][0] * sc); pk.y = f2bf(acc[mi][ni][1] * sc);
      pk.z = f2bf(acc[mi][ni][2] * sc); pk.w = f2bf(acc[mi][ni][3] * sc);
      *(ushort4*)&lg[((size_t)bz << 20) + (size_t)col * 1024 + r0 + mi * 16] = pk;
    }
}

// out = ao @ Wproj + bproj + x, computed as C^T -> float4 stores along outdim.
__global__ __launch_bounds__(256) void k_gemm_out(
    const unsigned short* __restrict__ ao, const unsigned short* __restrict__ wtp,
    const float* __restrict__ bproj, const float* __restrict__ xres,
    float* __restrict__ out) {
  const int tm = blockIdx.x * 64, tn = blockIdx.y * 128;
  GEMM_PROLOGUE(2, 4);
  gemm_core_t<2, 4>(wtp + (size_t)tm * 1024, ao + (size_t)tn * 1024, ldsA, ldsB, acc);
  GEMM_EPI_IDX(2, 4);
#pragma unroll
  for (int mi = 0; mi < 2; ++mi) {
    const float4 b4 = *(const float4*)&bproj[r0 + mi * 16];
#pragma unroll
    for (int ni = 0; ni < 4; ++ni) {
      const int seq = c0 + ni * 16;
      const size_t idx = (size_t)seq * 1024 + r0 + mi * 16;
      const float4 rv = *(const float4*)&xres[idx];
      float4 ov;
      ov.x = acc[mi][ni][0] + b4.x + rv.x;
      ov.y = acc[mi][ni][1] + b4.y + rv.y;
      ov.z = acc[mi][ni][2] + b4.z + rv.z;
      ov.w = acc[mi][ni][3] + b4.w + rv.w;
      *(float4*)&out[idx] = ov;
    }
  }
}

// ---------- fused flash attention: S^T = K q^T, O^T = V^T P^T --------------
// P never touches LDS: its MFMA C-layout (q on lane15, kv on quad*4+rr) is
// converted to the PV B-operand layout (q on lane15, kv on quad*8+j) with 8
// __shfl + 4 cndmask per 32-kv step. Only 2 barriers/chunk remain (staging).
// O^T has q on lane15 -> 1/l normalize needs no shuffles; store is ushort4.
// Fixed-offset softmax P = exp2(s - SOFT_OFF). XCD swizzle: xcd = b*2 + h/8.
__global__ __launch_bounds__(256, 5) void k_attn(
    const unsigned short* __restrict__ qb, const unsigned short* __restrict__ kb,
    const unsigned short* __restrict__ vt, const unsigned short* __restrict__ lg,
    unsigned short* __restrict__ ao) {
  __shared__ unsigned short ldsK[128 * 64];  // [kv][d] swz ^(kv&7)
  __shared__ unsigned short ldsV[64 * 128];  // [d][kv] swz ^(d&15)
  const int bid = blockIdx.x;
  const int xcd = bid & 7, idx = bid >> 3;
  const int b = xcd >> 1, hg = xcd & 1;
  const int h = hg * 8 + (idx >> 4);
  const int q0 = (idx & 15) * 64;
  const int tid = threadIdx.x, w = tid >> 6, lane = tid & 63;
  const int lane15 = lane & 15, quad = lane >> 4;
  const int qw = q0 + w * 16;
  const int src0 = (quad & 1) * 32 + lane15;  // P-transpose shuffle sources
  const int src1 = src0 + 16;
  const bool hiq = quad >= 2;

  bf16x8 qf[2];
  {
    const unsigned short* qrow =
        qb + (size_t)((b << 10) + qw + lane15) * 1024 + (h << 6);
    qf[0] = *(const bf16x8*)(qrow + quad * 8);
    qf[1] = *(const bf16x8*)(qrow + 32 + quad * 8);
  }
  float lcol = 0.f;  // per-lane partial sum of P (q = lane15)
  f32x4 o[4];        // O^T tiles: row d = dt*16+quad*4+rr, col q = lane15
  {
    f32x4 z_ = {0.f, 0.f, 0.f, 0.f};
#pragma unroll
    for (int nt = 0; nt < 4; ++nt) o[nt] = z_;
  }

  for (int c = 0; c < 8; ++c) {
    const int kv0 = c * 128;
    __syncthreads();  // prev chunk LDS reads complete
#pragma unroll
    for (int i = 0; i < 4; ++i) {
      const int p = i * 256 + tid;
      {
        const int r = p >> 3, cc = (p & 7) ^ (r & 7);
        async_lds16(kb + (size_t)((b << 10) + kv0 + r) * 1024 + (h << 6) + cc * 8,
                    ldsK + (i * 256 + w * 64) * 8);
      }
      {
        const int r = p >> 4, cc = (p & 15) ^ (r & 15);
        async_lds16(vt + (size_t)(((b * 16 + h) << 6) + r) * 1024 + kv0 + cc * 8,
                    ldsV + (i * 256 + w * 64) * 8);
      }
    }
    uint2 lgv[8];
    {
      const unsigned short* lgrow =
          lg + ((size_t)b << 20) + (size_t)(qw + lane15) * 1024 + kv0 + quad * 4;
#pragma unroll
      for (int mi = 0; mi < 8; ++mi) lgv[mi] = *(const uint2*)(lgrow + mi * 16);
    }
    __syncthreads();  // staging visible

    // S^T = K q^T, accumulator seeded with bias
    f32x4 s[8];
#pragma unroll
    for (int mi = 0; mi < 8; ++mi) {
      const int row = mi * 16 + lane15;
      bf16x8 k0 = *(const bf16x8*)&ldsK[row * 64 + ((quad ^ (row & 7)) << 3)];
      bf16x8 k1 = *(const bf16x8*)&ldsK[row * 64 + (((4 + quad) ^ (row & 7)) << 3)];
      f32x4 t;
      t[0] = __uint_as_float(lgv[mi].x << 16);
      t[1] = __uint_as_float(lgv[mi].x & 0xffff0000u);
      t[2] = __uint_as_float(lgv[mi].y << 16);
      t[3] = __uint_as_float(lgv[mi].y & 0xffff0000u);
      t = MFMA(k0, qf[0], t);
      t = MFMA(k1, qf[1], t);
      s[mi] = t;
    }
    // P = exp2(s - OFF), fully parallel; per-lane l partials; pack bf16 pairs
    float rs = 0.f;
    uint2 pk[8];
#pragma unroll
    for (int mi = 0; mi < 8; ++mi) {
      const float p0 = exp2f(s[mi][0] - SOFT_OFF), p1 = exp2f(s[mi][1] - SOFT_OFF);
      const float p2 = exp2f(s[mi][2] - SOFT_OFF), p3 = exp2f(s[mi][3] - SOFT_OFF);
      rs += (p0 + p1) + (p2 + p3);
      pk[mi].x = ((__float_as_uint(p1) + 0x8000u) & 0xffff0000u) |
                 ((__float_as_uint(p0) + 0x8000u) >> 16);
      pk[mi].y = ((__float_as_uint(p3) + 0x8000u) & 0xffff0000u) |
                 ((__float_as_uint(p2) + 0x8000u) >> 16);
    }
    lcol += rs;

    // O^T += V^T P^T : A = V^T rows from LDS, B = P^T built via shuffles.
    // Lane needs kv = quad*8+j (j=0..7) of tile t = 2kp + (quad>=2), held by
    // src lanes (quad&1)*32+lane15 (j<4) and +16 (j>=4), regs .x/.y = j%4.
#pragma unroll
    for (int kp = 0; kp < 4; ++kp) {
      const unsigned x0a = __shfl(pk[2 * kp].x, src0);
      const unsigned y0a = __shfl(pk[2 * kp].y, src0);
      const unsigned x1a = __shfl(pk[2 * kp].x, src1);
      const unsigned y1a = __shfl(pk[2 * kp].y, src1);
      const unsigned x0b = __shfl(pk[2 * kp + 1].x, src0);
      const unsigned y0b = __shfl(pk[2 * kp + 1].y, src0);
      const unsigned x1b = __shfl(pk[2 * kp + 1].x, src1);
      const unsigned y1b = __shfl(pk[2 * kp + 1].y, src1);
      uint4 bfv;
      bfv.x = hiq ? x0b : x0a;
      bfv.y = hiq ? y0b : y0a;
      bfv.z = hiq ? x1b : x1a;
      bfv.w = hiq ? y1b : y1a;
      const bf16x8 pf = __builtin_bit_cast(bf16x8, bfv);
#pragma unroll
      for (int dt = 0; dt < 4; ++dt) {
        const int d = dt * 16 + lane15;
        bf16x8 vf = *(const bf16x8*)&ldsV[d * 128 +
                                          (((kp * 4 + quad) ^ (d & 15)) << 3)];
        o[dt] = MFMA(vf, pf, o[dt]);
      }
    }
  }
  // l reduce over quads; normalize (q = lane15, no shuffles); ushort4 store
  lcol += __shfl_xor(lcol, 16);
  lcol += __shfl_xor(lcol, 32);
  const float rinv = 1.0f / lcol;
  const int m = (b << 10) + qw + lane15;
#pragma unroll
  for (int dt = 0; dt < 4; ++dt) {
    ushort4 pkk;
    pkk.x = f2bf(o[dt][0] * rinv);
    pkk.y = f2bf(o[dt][1] * rinv);
    pkk.z = f2bf(o[dt][2] * rinv);
    pkk.w = f2bf(o[dt][3] * rinv);
    *(ushort4*)&ao[(size_t)m * 1024 + (h << 6) + dt * 16 + quad * 4] = pkk;
  }
}

// ---------- launch ----------
extern "C" void kernel_launch(void* const* d_in, const int* in_sizes, int n_in,
                              void* d_out, int out_size, void* d_ws, size_t ws_size,
                              hipStream_t stream) {
  const float* x     = (const float*)d_in[0];
  const float* Wq    = (const float*)d_in[1];
  const float* Wk    = (const float*)d_in[2];
  const float* Wv    = (const float*)d_in[3];
  const float* Wproj = (const float*)d_in[4];
  const float* bproj = (const float*)d_in[5];
  const float* Wpre  = (const float*)d_in[6];
  const float* bpre  = (const float*)d_in[7];
  const float* pi    = (const float*)d_in[8];
  float* out = (float*)d_out;
  char* ws = (char*)d_ws;

  unsigned short* xb  = (unsigned short*)(ws);               // 8 MB (later: lg)
  unsigned short* wt  = (unsigned short*)(ws + (8u << 20));  // 10 MB
  unsigned short* pre = (unsigned short*)(ws + (18u << 20)); // 8 MB (later: ao)
  unsigned short* qb  = (unsigned short*)(ws + (26u << 20)); // 8 MB
  unsigned short* kb  = (unsigned short*)(ws + (34u << 20)); // 8 MB
  unsigned short* vt  = (unsigned short*)(ws + (42u << 20)); // 8 MB
  unsigned short* lg  = xb;   // xb dead after k_gemm_qkvpre
  unsigned short* ao  = pre;  // pre dead after k_gemm_logits

  k_prep<<<dim3(4096 + 5120), dim3(256), 0, stream>>>(
      (const float4*)x, (ushort4*)xb, Wpre, Wq, Wk, Wv, Wproj, wt);
  k_gemm_qkvpre<<<dim3(1024), dim3(256), 0, stream>>>(xb, wt, bpre, pre, qb, kb, vt);
  k_gemm_logits<<<dim3(8, 16, 4), dim3(256), 0, stream>>>(pre, pi, lg);
  k_attn<<<dim3(1024), dim3(256), 0, stream>>>(qb, kb, vt, lg, ao);
  k_gemm_out<<<dim3(16, 32, 1), dim3(256), 0, stream>>>(ao, wt + 4 * (1u << 20), bproj, x, out);
}